// Round 3
// baseline (617.895 us; speedup 1.0000x reference)
//
#include <hip/hip_runtime.h>
#include <hip/hip_bf16.h>
#include <cstdint>

#define B_   16
#define N_   1369
#define NP   1536
#define D_   1024
#define NQKV 3072

typedef __bf16 bf16x8_t __attribute__((ext_vector_type(8)));
typedef __bf16 bf16x4_t __attribute__((ext_vector_type(4)));
typedef float  f32x4_t  __attribute__((ext_vector_type(4)));

__device__ __forceinline__ float  bf2f(__bf16 x) { return (float)x; }
__device__ __forceinline__ __bf16 f2bf(float x)  { return (__bf16)x; }

#define GLOAD_LDS16(g, l) __builtin_amdgcn_global_load_lds( \
    (const __attribute__((address_space(1))) void*)(g),     \
    (__attribute__((address_space(3))) void*)(l), 16, 0, 0)

// ---------------------------------------------------------------- pos table
__global__ __launch_bounds__(256)
void pos_kernel(float* __restrict__ pos)
{
    const int idx = blockIdx.x * 256 + threadIdx.x;
    if (idx >= N_ * D_) return;
    const int n = idx >> 10, f = idx & 1023;
    const int row = n / 37, col = n - row * 37;
    const float base = (f < 512) ? (float)row : (float)col;
    const int  t2   = (f & 511) >> 1;
    const float dv  = __expf(-0.03597789207803197f * (float)t2);
    const float ang = base * dv;
    pos[idx] = (f & 1) ? cosf(ang) : sinf(ang);
}

// ----------------------------------------------- x = patch + pos, cast bf16
__global__ __launch_bounds__(256)
void addpos_kernel(const float* __restrict__ patch, const float* __restrict__ pos,
                   __bf16* __restrict__ X)
{
    const long tid = (long)blockIdx.x * 256 + threadIdx.x;
    const long e   = tid * 4;                 // element index in [B,NP,D]
    const int  f   = (int)(e & 1023);
    const long nb  = e >> 10;                 // b*NP + n
    const int  n   = (int)(nb % NP);
    const long b   = nb / NP;
    bf16x4_t o;
    if (n < N_) {
        const float4 p = *(const float4*)(patch + ((b * N_ + n) << 10) + f);
        const float4 q = *(const float4*)(pos + ((long)n << 10) + f);
        o[0] = f2bf(p.x + q.x); o[1] = f2bf(p.y + q.y);
        o[2] = f2bf(p.z + q.z); o[3] = f2bf(p.w + q.w);
    } else {
        o[0] = o[1] = o[2] = o[3] = f2bf(0.f);  // zero pad rows
    }
    *(bf16x4_t*)(X + e) = o;
}

// ------------------------------------ W[i][o] -> WT[o][i] bf16 (3 matrices)
__global__ __launch_bounds__(256)
void wcast_kernel(const float* __restrict__ W0, const float* __restrict__ W1,
                  const float* __restrict__ W2,
                  __bf16* __restrict__ T0, __bf16* __restrict__ T1, __bf16* __restrict__ T2)
{
    const float* W = blockIdx.z == 0 ? W0 : (blockIdx.z == 1 ? W1 : W2);
    __bf16*      T = blockIdx.z == 0 ? T0 : (blockIdx.z == 1 ? T1 : T2);
    __shared__ float tile[64][65];
    const int o0 = blockIdx.x * 64, i0 = blockIdx.y * 64;
    const int t = threadIdx.x;
    const int tr = t >> 4, tc = (t & 15) * 4;
    #pragma unroll
    for (int rr = 0; rr < 64; rr += 16) {
        float4 v = *(const float4*)(W + (long)(i0 + rr + tr) * 1024 + o0 + tc);
        tile[rr + tr][tc + 0] = v.x; tile[rr + tr][tc + 1] = v.y;
        tile[rr + tr][tc + 2] = v.z; tile[rr + tr][tc + 3] = v.w;
    }
    __syncthreads();
    #pragma unroll
    for (int rr = 0; rr < 64; rr += 16) {
        bf16x4_t o;
        o[0] = f2bf(tile[tc + 0][rr + tr]); o[1] = f2bf(tile[tc + 1][rr + tr]);
        o[2] = f2bf(tile[tc + 2][rr + tr]); o[3] = f2bf(tile[tc + 3][rr + tr]);
        *(bf16x4_t*)(T + (long)(o0 + rr + tr) * 1024 + i0 + tc) = o;
    }
}

// ---------------------------------------------- bias concat [bq|bk|bv] 3072
__global__ __launch_bounds__(256)
void bcat_kernel(const float* __restrict__ bq, const float* __restrict__ bk,
                 const float* __restrict__ bv, float* __restrict__ bcat)
{
    const int i = blockIdx.x * 256 + threadIdx.x;
    if (i >= NQKV) return;
    const int p = i >> 10, j = i & 1023;
    bcat[i] = p == 0 ? bq[j] : (p == 1 ? bk[j] : bv[j]);
}

// ------------------------------------------------------- 256^2 4-phase GEMM
// A 3-buffered / B 2-buffered (160 KiB LDS) for deep prefetch:
//   iter t stages A(t+2) at P0/P1 (buf (t+2)%3, holds consumed A(t-1)),
//   B(t+2) at P2/P3 (buf t&1; B(t) fully consumed at P0), vmcnt(8) at P3.
// A prefetch distance ~7-8 phases, B ~4-5 -- covers HBM latency.
// st_16x32-style swizzle via inverse-swizzled global source + swizzled ds_read.
template<int HAS_BIAS>
__global__ __launch_bounds__(512, 2)
void gemm256(const __bf16* __restrict__ A, const __bf16* __restrict__ Bt,
             __bf16* __restrict__ C, const float* __restrict__ bias,
             int lda, int ldb, int ldc, int Kd, float scale,
             long sA, long sB, long sC, int tilesN, int tilesPerBatch, int cpx)
{
    __shared__ __bf16 lds[81920];   // 160 KiB: A 3x16384 | B 2x16384 (+49152)
    const int bid = blockIdx.x;
    const int vt  = (bid & 7) * cpx + (bid >> 3);      // XCD-bijective (nwg%8==0)
    const int bz  = vt / tilesPerBatch;
    const int rem = vt - bz * tilesPerBatch;
    const int ty  = rem / tilesN;
    const int tx  = rem - ty * tilesN;
    A  += (long)bz * sA;  Bt += (long)bz * sB;  C += (long)bz * sC;
    const int m0 = ty * 256, n0 = tx * 256;

    const int t  = threadIdx.x;
    const int w  = t >> 6, l = t & 63;
    const int wr = w >> 2, wc = w & 3;         // 2 x 4 wave grid
    const int lr = l & 15, lh = l >> 4;

    // swizzled ds_read lane offset (elems)
    const int laneF  = (lr * 64 + ((lh * 16) ^ (((lr >> 3) & 1) << 5))) >> 1;
    // staging source mapping (inverse swizzle)
    const int rstage = w * 16 + (l >> 2);
    const int kstage = ((l & 3) * 8) ^ (((l >> 5) & 1) << 4);

    const __bf16* Ag = A  + (long)(m0 + rstage) * lda + kstage;
    const __bf16* Bg = Bt + (long)(n0 + rstage) * ldb + kstage;
    __bf16* dA = lds + w * 1024;            // + abuf*16384 + half*8192
    __bf16* dB = lds + 49152 + w * 1024;    // + bbuf*16384 + half*8192

#define SA_(buf, half, kt) do {                                       \
    const __bf16* g_ = Ag + (long)(half) * 128 * lda + (kt) * 64;     \
    __bf16* d_ = dA + (buf) * 16384 + (half) * 8192;                  \
    GLOAD_LDS16(g_, d_); GLOAD_LDS16(g_ + 32, d_ + 512); } while (0)
#define SB_(buf, half, kt) do {                                       \
    const __bf16* g_ = Bg + (long)(half) * 128 * ldb + (kt) * 64;     \
    __bf16* d_ = dB + (buf) * 16384 + (half) * 8192;                  \
    GLOAD_LDS16(g_, d_); GLOAD_LDS16(g_ + 32, d_ + 512); } while (0)

    f32x4_t acc[8][4] = {};
    bf16x8_t bfr[4][2];

#define BREADS_() do { const __bf16* bp_ = lds + cbB + laneF;                              \
    bfr[0][0] = *(const bf16x8_t*)(bp_);        bfr[0][1] = *(const bf16x8_t*)(bp_ + 512); \
    bfr[1][0] = *(const bf16x8_t*)(bp_ + 1024); bfr[1][1] = *(const bf16x8_t*)(bp_ + 1536);\
    bfr[2][0] = *(const bf16x8_t*)(bp_ + 2048); bfr[2][1] = *(const bf16x8_t*)(bp_ + 2560);\
    bfr[3][0] = *(const bf16x8_t*)(bp_ + 3072); bfr[3][1] = *(const bf16x8_t*)(bp_ + 3584);} while (0)

#define PHASE_(p, P0R, STG, VMW) do {                                                  \
    const __bf16* ap_ = lds + cbase + wr * 8192 + (p) * 2048 + laneF;                  \
    bf16x8_t a00 = *(const bf16x8_t*)(ap_);                                            \
    bf16x8_t a01 = *(const bf16x8_t*)(ap_ + 512);                                      \
    bf16x8_t a10 = *(const bf16x8_t*)(ap_ + 1024);                                     \
    bf16x8_t a11 = *(const bf16x8_t*)(ap_ + 1536);                                     \
    P0R;                                                                               \
    STG;                                                                               \
    __builtin_amdgcn_s_barrier();                                                      \
    asm volatile("s_waitcnt lgkmcnt(0)" ::: "memory");                                 \
    __builtin_amdgcn_sched_barrier(0);                                                 \
    __builtin_amdgcn_s_setprio(1);                                                     \
    _Pragma("unroll") for (int nn = 0; nn < 4; ++nn)                                   \
      acc[(p)*2+0][nn] = __builtin_amdgcn_mfma_f32_16x16x32_bf16(a00, bfr[nn][0], acc[(p)*2+0][nn], 0, 0, 0); \
    _Pragma("unroll") for (int nn = 0; nn < 4; ++nn)                                   \
      acc[(p)*2+1][nn] = __builtin_amdgcn_mfma_f32_16x16x32_bf16(a10, bfr[nn][0], acc[(p)*2+1][nn], 0, 0, 0); \
    _Pragma("unroll") for (int nn = 0; nn < 4; ++nn)                                   \
      acc[(p)*2+0][nn] = __builtin_amdgcn_mfma_f32_16x16x32_bf16(a01, bfr[nn][1], acc[(p)*2+0][nn], 0, 0, 0); \
    _Pragma("unroll") for (int nn = 0; nn < 4; ++nn)                                   \
      acc[(p)*2+1][nn] = __builtin_amdgcn_mfma_f32_16x16x32_bf16(a11, bfr[nn][1], acc[(p)*2+1][nn], 0, 0, 0); \
    __builtin_amdgcn_s_setprio(0);                                                     \
    VMW;                                                                               \
    __builtin_amdgcn_s_barrier();                                                      \
  } while (0)

    const int NT = Kd >> 6;
    // prologue: tiles 0 and 1 fully staged (16 gloads/wave), tile0 must land
    SA_(0, 0, 0); SA_(0, 1, 0); SB_(0, 0, 0); SB_(0, 1, 0);
    SA_(1, 0, 1); SA_(1, 1, 1); SB_(1, 0, 1); SB_(1, 1, 1);
    asm volatile("s_waitcnt vmcnt(8)" ::: "memory");
    __builtin_amdgcn_s_barrier();

    int ab = 0;                                // tk % 3
    for (int tk = 0; tk < NT; ++tk) {
        const int bb = tk & 1;
        const int st = (tk + 2 < NT);
        const int a2 = (ab + 2 >= 3) ? ab - 1 : ab + 2;   // (tk+2)%3
        const int cbase = ab * 16384;
        const int cbB   = 49152 + bb * 16384 + wc * 4096;
        PHASE_(0, BREADS_(), if (st) SA_(a2, 0, tk + 2), ((void)0));
        PHASE_(1, ((void)0), if (st) SA_(a2, 1, tk + 2), ((void)0));
        PHASE_(2, ((void)0), if (st) SB_(bb, 0, tk + 2), ((void)0));
        PHASE_(3, ((void)0), if (st) SB_(bb, 1, tk + 2),
               if (st) { asm volatile("s_waitcnt vmcnt(8)" ::: "memory"); }
               else    { asm volatile("s_waitcnt vmcnt(0)" ::: "memory"); });
        ab = (ab + 1 == 3) ? 0 : ab + 1;
    }

    // epilogue: C/D layout col=lane&15, row=(lane>>4)*4+reg
    #pragma unroll
    for (int mi = 0; mi < 8; ++mi) {
        const int row = m0 + wr * 128 + mi * 16 + lh * 4;
        #pragma unroll
        for (int nn = 0; nn < 4; ++nn) {
            const int col = n0 + wc * 64 + nn * 16 + lr;
            const float bb2 = HAS_BIAS ? bias[col] : 0.0f;
            #pragma unroll
            for (int q = 0; q < 4; ++q)
                C[(long)(row + q) * ldc + col] = f2bf(acc[mi][nn][q] * scale + bb2);
        }
    }
#undef SA_
#undef SB_
#undef BREADS_
#undef PHASE_
}

// ------------------------------------------------- row softmax, in place
// 256 threads; lanes t<192 each own one bf16x8 slice of the 1536-col row.
__global__ __launch_bounds__(256)
void softmax_kernel(__bf16* __restrict__ S)
{
    const int q = blockIdx.x, b = blockIdx.y;
    __bf16* row = S + ((long)b * NP + q) * NP;
    const int t = threadIdx.x;
    const int k8 = t * 8;
    float v[8];
    float m = -1e30f;
    if (t < 192) {
        bf16x8_t raw = *(const bf16x8_t*)(row + k8);
        #pragma unroll
        for (int i = 0; i < 8; ++i) {
            const float x = (k8 + i < N_) ? bf2f(raw[i]) : -1e30f;
            v[i] = x; m = fmaxf(m, x);
        }
    }
    __shared__ float red[8];
    #pragma unroll
    for (int o = 32; o; o >>= 1) m = fmaxf(m, __shfl_xor(m, o));
    if (!(t & 63)) red[t >> 6] = m;
    __syncthreads();
    m = fmaxf(fmaxf(red[0], red[1]), fmaxf(red[2], red[3]));
    float s = 0.f;
    if (t < 192) {
        #pragma unroll
        for (int i = 0; i < 8; ++i) {
            if (k8 + i < N_) { const float e = __expf(v[i] - m); v[i] = e; s += e; }
        }
    }
    #pragma unroll
    for (int o = 32; o; o >>= 1) s += __shfl_xor(s, o);
    if (!(t & 63)) red[4 + (t >> 6)] = s;
    __syncthreads();
    s = red[4] + red[5] + red[6] + red[7];
    const float inv = 1.f / s;
    if (t < 192) {
        bf16x8_t o8;
        #pragma unroll
        for (int i = 0; i < 8; ++i)
            o8[i] = f2bf((k8 + i < N_) ? v[i] * inv : 0.f);
        *(bf16x8_t*)(row + k8) = o8;
    }
}

// --------------------- weighted column sums over attn (q-chunked + atomic)
// lanes t<192 each own 8 columns (bf16x8 loads, 1KB/wave-instr).
template<int WEIGHTED>
__global__ __launch_bounds__(256)
void colsum_kernel(const __bf16* __restrict__ attn, const float* __restrict__ wv,
                   float* __restrict__ out)
{
    const int t = threadIdx.x;
    if (t >= 192) return;
    const int b  = blockIdx.y;
    const int q0 = blockIdx.x * 16;
    const int q1 = (q0 + 16 < N_) ? q0 + 16 : N_;
    const int k8 = t * 8;
    float s[8] = {};
    const __bf16* base = attn + (long)b * NP * NP + k8;
    for (int q = q0; q < q1; ++q) {
        bf16x8_t v = *(const bf16x8_t*)(base + (long)q * NP);
        const float wq = WEIGHTED ? wv[b * NP + q] : 1.0f;
        #pragma unroll
        for (int i = 0; i < 8; ++i) s[i] += wq * bf2f(v[i]);
    }
    #pragma unroll
    for (int i = 0; i < 8; ++i) atomicAdd(out + b * NP + k8 + i, s[i]);
}

// ------------------- pa -> normalize -> curiosity modulation -> fa (output)
// var(pa) dominated by center-bias variance (~5e-3 >> 1e-6): branch 1 only.
__global__ __launch_bounds__(256)
void fa_kernel(const float* __restrict__ pa_raw, const float* __restrict__ curiosity,
               const float* __restrict__ Wc1, const float* __restrict__ bc1,
               const float* __restrict__ Wc2, const float* __restrict__ bc2,
               const float* __restrict__ aw_p,
               float* __restrict__ fa_ws, float* __restrict__ out_fa)
{
    const int b = blockIdx.x, t = threadIdx.x;
    __shared__ float hsh[64];
    __shared__ float red[8];
    __shared__ float cwsh;
    if (t < 64) hsh[t] = fmaxf(0.f, curiosity[b] * Wc1[t] + bc1[t]);
    __syncthreads();
    if (t < 8) {
        float a = bc2[t];
        for (int j = 0; j < 64; ++j) a += hsh[j] * Wc2[j * 8 + t];
        red[t] = 1.f / (1.f + __expf(-a));
    }
    __syncthreads();
    if (t == 0) {
        float cw = 0.f;
        for (int i = 0; i < 8; ++i) cw += red[i];
        cwsh = cw * 0.125f;
    }
    __syncthreads();
    const float aw   = aw_p[0];
    const float modf = 1.f + aw * cwsh;
    const float sig  = 37.f / 6.f;
    const float inv2s2 = 1.f / (2.f * sig * sig);
    float pv[6];
    float s1 = 0.f;
    #pragma unroll
    for (int i = 0; i < 6; ++i) {
        const int k = t + i * 256;
        float p = 0.f;
        if (k < N_) {
            const int y = k / 37, x = k - y * 37;
            const float d2 = (float)((x - 18) * (x - 18) + (y - 18) * (y - 18));
            const float cb = 0.3f * __expf(-d2 * inv2s2);
            p = pa_raw[b * NP + k] * (1.f / 1369.f) + cb;
        }
        pv[i] = p; s1 += p;
    }
    #pragma unroll
    for (int o = 32; o; o >>= 1) s1 += __shfl_xor(s1, o);
    __syncthreads();
    if (!(t & 63)) red[t >> 6] = s1;
    __syncthreads();
    s1 = red[0] + red[1] + red[2] + red[3];
    const float inv1 = 1.f / (s1 + 1e-8f);
    float s2 = 0.f;
    #pragma unroll
    for (int i = 0; i < 6; ++i) {
        const int k = t + i * 256;
        if (k < N_) {
            const float f = fmaxf(pv[i] * inv1 * modf, 1e-8f);
            pv[i] = f; s2 += f;
        }
    }
    #pragma unroll
    for (int o = 32; o; o >>= 1) s2 += __shfl_xor(s2, o);
    if (!(t & 63)) red[4 + (t >> 6)] = s2;
    __syncthreads();
    s2 = red[4] + red[5] + red[6] + red[7];
    const float inv2 = 1.f / (s2 + 1e-8f);
    #pragma unroll
    for (int i = 0; i < 6; ++i) {
        const int k = t + i * 256;
        if (k < N_) {
            const float f = pv[i] * inv2;
            fa_ws[b * NP + k]  = f;
            out_fa[b * N_ + k] = f;
        }
    }
}

// ------------------------------------- weighted[b,d] = sum_k g[b,k]*V[b,k,d]
__global__ __launch_bounds__(256)
void weighted_kernel(const float* __restrict__ g, const __bf16* __restrict__ V,
                     int ldv, float* __restrict__ wout)
{
    const int b  = blockIdx.y;
    const int k0 = blockIdx.x * 86;
    const int k1 = (k0 + 86 < N_) ? k0 + 86 : N_;
    const int d  = threadIdx.x * 4;
    float a0 = 0, a1 = 0, a2 = 0, a3 = 0;
    const __bf16* vb = V + (long)b * NP * ldv + d;
    for (int k = k0; k < k1; ++k) {
        const float gv = g[b * NP + k];
        bf16x4_t vv = *(const bf16x4_t*)(vb + (long)k * ldv);
        a0 += gv * bf2f(vv[0]); a1 += gv * bf2f(vv[1]);
        a2 += gv * bf2f(vv[2]); a3 += gv * bf2f(vv[3]);
    }
    atomicAdd(wout + b * D_ + d + 0, a0);
    atomicAdd(wout + b * D_ + d + 1, a1);
    atomicAdd(wout + b * D_ + d + 2, a2);
    atomicAdd(wout + b * D_ + d + 3, a3);
}

// -------------------------- focal = relu(weighted@Wp1+bp1)@Wp2+bp2  (fp32)
__global__ __launch_bounds__(256)
void focal_kernel(const float* __restrict__ weighted, const float* __restrict__ Wp1,
                  const float* __restrict__ bp1, const float* __restrict__ Wp2,
                  const float* __restrict__ bp2, float* __restrict__ out)
{
    const int b = blockIdx.x, t = threadIdx.x;
    __shared__ float wsh[1024];
    __shared__ float hsh[512];
    for (int i = t; i < 1024; i += 256) wsh[i] = weighted[b * 1024 + i];
    __syncthreads();
    for (int j = t; j < 512; j += 256) {
        float a = bp1[j];
        for (int d2 = 0; d2 < 1024; ++d2) a += wsh[d2] * Wp1[d2 * 512 + j];
        hsh[j] = fmaxf(a, 0.f);
    }
    __syncthreads();
    for (int o = t; o < 128; o += 256) {
        float a = bp2[o];
        for (int j = 0; j < 512; ++j) a += hsh[j] * Wp2[j * 128 + o];
        out[b * 128 + o] = a;
    }
}

// ---------------------------------------------------------------- launcher
extern "C" void kernel_launch(void* const* d_in, const int* in_sizes, int n_in,
                              void* d_out, int out_size, void* d_ws, size_t ws_size,
                              hipStream_t stream)
{
    const float* patch     = (const float*)d_in[0];
    const float* curiosity = (const float*)d_in[1];
    const float* Wq  = (const float*)d_in[2];
    const float* bq  = (const float*)d_in[3];
    const float* Wk  = (const float*)d_in[4];
    const float* bk  = (const float*)d_in[5];
    const float* Wv  = (const float*)d_in[6];
    const float* bv  = (const float*)d_in[7];
    const float* Wc1 = (const float*)d_in[8];
    const float* bc1 = (const float*)d_in[9];
    const float* Wc2 = (const float*)d_in[10];
    const float* bc2 = (const float*)d_in[11];
    const float* Wp1 = (const float*)d_in[12];
    const float* bp1 = (const float*)d_in[13];
    const float* Wp2 = (const float*)d_in[14];
    const float* bp2 = (const float*)d_in[15];
    const float* aw  = (const float*)d_in[16];
    float* out = (float*)d_out;

    char* ws = (char*)d_ws;
    size_t off = 0;
    auto alloc = [&](size_t bytes) -> char* {
        char* p = ws + off;
        off += (bytes + 255) & ~(size_t)255;
        return p;
    };
    // region 0: {pos, X, WT} -- later aliased by S (all fully rewritten each call)
    float*  pos  = (float*) alloc((size_t)N_ * D_ * 4);                 // 5.6 MB
    __bf16* X    = (__bf16*)alloc((size_t)B_ * NP * D_ * 2);            // 50.3 MB
    __bf16* WT   = (__bf16*)alloc((size_t)3 * D_ * D_ * 2);             // 6.3 MB
    const size_t S_BYTES = (size_t)B_ * NP * NP * 2;                    // 75.5 MB
    if (off < S_BYTES) off = S_BYTES;
    __bf16* S    = (__bf16*)ws;                                         // alias region 0
    __bf16* QKV  = (__bf16*)alloc((size_t)B_ * NP * NQKV * 2);          // 151 MB
    float*  pa   = (float*) alloc((size_t)B_ * NP * 4);
    float*  faw  = (float*) alloc((size_t)B_ * NP * 4);
    float*  gbuf = (float*) alloc((size_t)B_ * NP * 4);
    float*  wsum = (float*) alloc((size_t)B_ * D_ * 4);
    float*  bcat = (float*) alloc((size_t)NQKV * 4);

    (void)hipMemsetAsync(pa,   0, (size_t)B_ * NP * 4, stream);
    (void)hipMemsetAsync(gbuf, 0, (size_t)B_ * NP * 4, stream);
    (void)hipMemsetAsync(wsum, 0, (size_t)B_ * D_ * 4, stream);

    pos_kernel<<<(N_ * D_ + 255) / 256, 256, 0, stream>>>(pos);
    addpos_kernel<<<(int)((size_t)B_ * NP * D_ / 4 / 256), 256, 0, stream>>>(patch, pos, X);
    {
        dim3 g(16, 16, 3);
        wcast_kernel<<<g, 256, 0, stream>>>(Wq, Wk, Wv,
                                            WT, WT + D_ * D_, WT + 2 * D_ * D_);
    }
    bcat_kernel<<<(NQKV + 255) / 256, 256, 0, stream>>>(bq, bk, bv, bcat);
    {
        // QKV projection: M=B*NP=24576(96), N=3072(12), K=1024 -> 1152 blocks
        const int nwg = 96 * 12;
        gemm256<1><<<nwg, 512, 0, stream>>>(X, WT, QKV, bcat,
                                            D_, D_, NQKV, D_, 1.0f,
                                            0, 0, 0, 12, nwg, nwg / 8);
    }
    {
        // scores: per batch M=N=1536(6x6), K=1024; 16 batches -> 576 blocks
        const int nwg = 36 * B_;
        gemm256<0><<<nwg, 512, 0, stream>>>(QKV, QKV + D_, S, nullptr,
                                            NQKV, NQKV, NP, D_,
                                            0.08838834764831845f,
                                            (long)NP * NQKV, (long)NP * NQKV,
                                            (long)NP * NP, 6, 36, nwg / 8);
    }
    {
        dim3 g(N_, B_);
        softmax_kernel<<<g, 256, 0, stream>>>(S);
    }
    {
        dim3 g(86, B_);
        colsum_kernel<0><<<g, 256, 0, stream>>>(S, nullptr, pa);
    }
    fa_kernel<<<B_, 256, 0, stream>>>(pa, curiosity, Wc1, bc1, Wc2, bc2, aw,
                                      faw, out + B_ * 128);
    {
        dim3 g(86, B_);
        colsum_kernel<1><<<g, 256, 0, stream>>>(S, faw, gbuf);
    }
    {
        dim3 g(16, B_);
        weighted_kernel<<<g, 256, 0, stream>>>(gbuf, QKV + 2 * D_, NQKV, wsum);
    }
    focal_kernel<<<B_, 256, 0, stream>>>(wsum, Wp1, bp1, Wp2, bp2, out);
}

// Round 4
// 599.489 us; speedup vs baseline: 1.0307x; 1.0307x over previous
//
#include <hip/hip_runtime.h>
#include <hip/hip_bf16.h>
#include <cstdint>

#define B_   16
#define N_   1369
#define NP   1536
#define D_   1024
#define NQKV 3072
#define SLD  1568   // S leading dim (3136B rows: odd multiple of 64B, no channel aliasing)
#define QLD  3104   // QKV leading dim (6208B rows)

typedef __bf16 bf16x8_t __attribute__((ext_vector_type(8)));
typedef __bf16 bf16x4_t __attribute__((ext_vector_type(4)));
typedef float  f32x4_t  __attribute__((ext_vector_type(4)));

__device__ __forceinline__ float  bf2f(__bf16 x) { return (float)x; }
__device__ __forceinline__ __bf16 f2bf(float x)  { return (__bf16)x; }

#define GLOAD_LDS16(g, l) __builtin_amdgcn_global_load_lds( \
    (const __attribute__((address_space(1))) void*)(g),     \
    (__attribute__((address_space(3))) void*)(l), 16, 0, 0)

// ---------------------------------------------------------------- pos table
__global__ __launch_bounds__(256)
void pos_kernel(float* __restrict__ pos)
{
    const int idx = blockIdx.x * 256 + threadIdx.x;
    if (idx >= N_ * D_) return;
    const int n = idx >> 10, f = idx & 1023;
    const int row = n / 37, col = n - row * 37;
    const float base = (f < 512) ? (float)row : (float)col;
    const int  t2   = (f & 511) >> 1;
    const float dv  = __expf(-0.03597789207803197f * (float)t2);
    const float ang = base * dv;
    pos[idx] = (f & 1) ? cosf(ang) : sinf(ang);
}

// ----------------------------------------------- x = patch + pos, cast bf16
__global__ __launch_bounds__(256)
void addpos_kernel(const float* __restrict__ patch, const float* __restrict__ pos,
                   __bf16* __restrict__ X)
{
    const long tid = (long)blockIdx.x * 256 + threadIdx.x;
    const long e   = tid * 4;                 // element index in [B,NP,D]
    const int  f   = (int)(e & 1023);
    const long nb  = e >> 10;                 // b*NP + n
    const int  n   = (int)(nb % NP);
    const long b   = nb / NP;
    bf16x4_t o;
    if (n < N_) {
        const float4 p = *(const float4*)(patch + ((b * N_ + n) << 10) + f);
        const float4 q = *(const float4*)(pos + ((long)n << 10) + f);
        o[0] = f2bf(p.x + q.x); o[1] = f2bf(p.y + q.y);
        o[2] = f2bf(p.z + q.z); o[3] = f2bf(p.w + q.w);
    } else {
        o[0] = o[1] = o[2] = o[3] = f2bf(0.f);  // zero pad rows
    }
    *(bf16x4_t*)(X + e) = o;
}

// ------------------------------------ W[i][o] -> WT[o][i] bf16 (3 matrices)
__global__ __launch_bounds__(256)
void wcast_kernel(const float* __restrict__ W0, const float* __restrict__ W1,
                  const float* __restrict__ W2,
                  __bf16* __restrict__ T0, __bf16* __restrict__ T1, __bf16* __restrict__ T2)
{
    const float* W = blockIdx.z == 0 ? W0 : (blockIdx.z == 1 ? W1 : W2);
    __bf16*      T = blockIdx.z == 0 ? T0 : (blockIdx.z == 1 ? T1 : T2);
    __shared__ float tile[64][65];
    const int o0 = blockIdx.x * 64, i0 = blockIdx.y * 64;
    const int t = threadIdx.x;
    const int tr = t >> 4, tc = (t & 15) * 4;
    #pragma unroll
    for (int rr = 0; rr < 64; rr += 16) {
        float4 v = *(const float4*)(W + (long)(i0 + rr + tr) * 1024 + o0 + tc);
        tile[rr + tr][tc + 0] = v.x; tile[rr + tr][tc + 1] = v.y;
        tile[rr + tr][tc + 2] = v.z; tile[rr + tr][tc + 3] = v.w;
    }
    __syncthreads();
    #pragma unroll
    for (int rr = 0; rr < 64; rr += 16) {
        bf16x4_t o;
        o[0] = f2bf(tile[tc + 0][rr + tr]); o[1] = f2bf(tile[tc + 1][rr + tr]);
        o[2] = f2bf(tile[tc + 2][rr + tr]); o[3] = f2bf(tile[tc + 3][rr + tr]);
        *(bf16x4_t*)(T + (long)(o0 + rr + tr) * 1024 + i0 + tc) = o;
    }
}

// ---------------------------------------------- bias concat [bq|bk|bv] 3072
__global__ __launch_bounds__(256)
void bcat_kernel(const float* __restrict__ bq, const float* __restrict__ bk,
                 const float* __restrict__ bv, float* __restrict__ bcat)
{
    const int i = blockIdx.x * 256 + threadIdx.x;
    if (i >= NQKV) return;
    const int p = i >> 10, j = i & 1023;
    bcat[i] = p == 0 ? bq[j] : (p == 1 ? bk[j] : bv[j]);
}

// ------------------------------------------------------- 256^2 4-phase GEMM
// (r2-verified schedule) BM=BN=256, BK=64, 512 thr (8 waves 2x4), LDS 128 KiB,
// st_16x32-style swizzle (inverse-swizzled global src + swizzled ds_read),
// counted vmcnt(4) once per K-tile, raw s_barrier, setprio around MFMA.
template<int HAS_BIAS>
__global__ __launch_bounds__(512, 2)
void gemm256(const __bf16* __restrict__ A, const __bf16* __restrict__ Bt,
             __bf16* __restrict__ C, const float* __restrict__ bias,
             int lda, int ldb, int ldc, int Kd, float scale,
             long sA, long sB, long sC, int tilesN, int tilesPerBatch, int cpx)
{
    __shared__ __bf16 lds[65536];   // 128 KiB
    const int bid = blockIdx.x;
    const int vt  = (bid & 7) * cpx + (bid >> 3);      // XCD-bijective (nwg%8==0)
    const int bz  = vt / tilesPerBatch;
    const int rem = vt - bz * tilesPerBatch;
    const int ty  = rem / tilesN;
    const int tx  = rem - ty * tilesN;
    A  += (long)bz * sA;  Bt += (long)bz * sB;  C += (long)bz * sC;
    const int m0 = ty * 256, n0 = tx * 256;

    const int t  = threadIdx.x;
    const int w  = t >> 6, l = t & 63;
    const int wr = w >> 2, wc = w & 3;         // 2 x 4 wave grid
    const int lr = l & 15, lh = l >> 4;

    // swizzled ds_read lane offset (elems): row lr, k-slice lh within 32-k half
    const int laneF  = (lr * 64 + ((lh * 16) ^ (((lr >> 3) & 1) << 5))) >> 1;
    // staging source mapping (inverse swizzle): lane l covers row rstage, k kstage..+8
    const int rstage = w * 16 + (l >> 2);
    const int kstage = ((l & 3) * 8) ^ (((l >> 5) & 1) << 4);

    const __bf16* Ag = A  + (long)(m0 + rstage) * lda + kstage;
    const __bf16* Bg = Bt + (long)(n0 + rstage) * ldb + kstage;
    __bf16* dA = lds + (w * 2) * 512;           // + buf*32768 + half*8192
    __bf16* dB = lds + 16384 + (w * 2) * 512;

#define SA_(buf, half, kt) do {                                       \
    const __bf16* g_ = Ag + (long)(half) * 128 * lda + (kt) * 64;     \
    __bf16* d_ = dA + (buf) * 32768 + (half) * 8192;                  \
    GLOAD_LDS16(g_, d_); GLOAD_LDS16(g_ + 32, d_ + 512); } while (0)
#define SB_(buf, half, kt) do {                                       \
    const __bf16* g_ = Bg + (long)(half) * 128 * ldb + (kt) * 64;     \
    __bf16* d_ = dB + (buf) * 32768 + (half) * 8192;                  \
    GLOAD_LDS16(g_, d_); GLOAD_LDS16(g_ + 32, d_ + 512); } while (0)

    f32x4_t acc[8][4] = {};
    bf16x8_t bfr[4][2];

#define BREADS_() do { const __bf16* bp_ = lds + cbB + laneF;                              \
    bfr[0][0] = *(const bf16x8_t*)(bp_);        bfr[0][1] = *(const bf16x8_t*)(bp_ + 512); \
    bfr[1][0] = *(const bf16x8_t*)(bp_ + 1024); bfr[1][1] = *(const bf16x8_t*)(bp_ + 1536);\
    bfr[2][0] = *(const bf16x8_t*)(bp_ + 2048); bfr[2][1] = *(const bf16x8_t*)(bp_ + 2560);\
    bfr[3][0] = *(const bf16x8_t*)(bp_ + 3072); bfr[3][1] = *(const bf16x8_t*)(bp_ + 3584);} while (0)

#define PHASE_(p, P0R, STG, VMW) do {                                                  \
    const __bf16* ap_ = lds + cbase + wr * 8192 + (p) * 2048 + laneF;                  \
    bf16x8_t a00 = *(const bf16x8_t*)(ap_);                                            \
    bf16x8_t a01 = *(const bf16x8_t*)(ap_ + 512);                                      \
    bf16x8_t a10 = *(const bf16x8_t*)(ap_ + 1024);                                     \
    bf16x8_t a11 = *(const bf16x8_t*)(ap_ + 1536);                                     \
    P0R;                                                                               \
    STG;                                                                               \
    __builtin_amdgcn_s_barrier();                                                      \
    asm volatile("s_waitcnt lgkmcnt(0)" ::: "memory");                                 \
    __builtin_amdgcn_sched_barrier(0);                                                 \
    __builtin_amdgcn_s_setprio(1);                                                     \
    _Pragma("unroll") for (int nn = 0; nn < 4; ++nn)                                   \
      acc[(p)*2+0][nn] = __builtin_amdgcn_mfma_f32_16x16x32_bf16(a00, bfr[nn][0], acc[(p)*2+0][nn], 0, 0, 0); \
    _Pragma("unroll") for (int nn = 0; nn < 4; ++nn)                                   \
      acc[(p)*2+1][nn] = __builtin_amdgcn_mfma_f32_16x16x32_bf16(a10, bfr[nn][0], acc[(p)*2+1][nn], 0, 0, 0); \
    _Pragma("unroll") for (int nn = 0; nn < 4; ++nn)                                   \
      acc[(p)*2+0][nn] = __builtin_amdgcn_mfma_f32_16x16x32_bf16(a01, bfr[nn][1], acc[(p)*2+0][nn], 0, 0, 0); \
    _Pragma("unroll") for (int nn = 0; nn < 4; ++nn)                                   \
      acc[(p)*2+1][nn] = __builtin_amdgcn_mfma_f32_16x16x32_bf16(a11, bfr[nn][1], acc[(p)*2+1][nn], 0, 0, 0); \
    __builtin_amdgcn_s_setprio(0);                                                     \
    VMW;                                                                               \
    __builtin_amdgcn_s_barrier();                                                      \
  } while (0)

    const int NT = Kd >> 6;
    // prologue: tile0 fully + tile1 B halves in flight
    SA_(0, 0, 0); SA_(0, 1, 0); SB_(0, 0, 0); SB_(0, 1, 0);
    SB_(1, 0, 1); SB_(1, 1, 1);
    asm volatile("s_waitcnt vmcnt(4)" ::: "memory");
    __builtin_amdgcn_s_barrier();

    for (int tk = 0; tk < NT; ++tk) {
        const int c  = tk & 1, o = c ^ 1;
        const int t1 = (tk + 1 < NT) ? tk + 1 : NT - 1;   // clamped dummy at tail
        const int t2 = (tk + 2 < NT) ? tk + 2 : NT - 1;
        const int cbase = c * 32768;
        const int cbB   = cbase + 16384 + wc * 4096;
        PHASE_(0, BREADS_(), SA_(o, 0, t1), ((void)0));
        PHASE_(1, ((void)0), SA_(o, 1, t1), ((void)0));
        PHASE_(2, ((void)0), SB_(c, 0, t2), ((void)0));
        PHASE_(3, ((void)0), SB_(c, 1, t2),
               asm volatile("s_waitcnt vmcnt(4)" ::: "memory"));
    }

    // epilogue: C/D layout col=lane&15, row=(lane>>4)*4+reg
    #pragma unroll
    for (int mi = 0; mi < 8; ++mi) {
        const int row = m0 + wr * 128 + mi * 16 + lh * 4;
        #pragma unroll
        for (int nn = 0; nn < 4; ++nn) {
            const int col = n0 + wc * 64 + nn * 16 + lr;
            const float bb = HAS_BIAS ? bias[col] : 0.0f;
            #pragma unroll
            for (int q = 0; q < 4; ++q)
                C[(long)(row + q) * ldc + col] = f2bf(acc[mi][nn][q] * scale + bb);
        }
    }
#undef SA_
#undef SB_
#undef BREADS_
#undef PHASE_
}

// ------------------------------------------------- row softmax, in place
// one WAVE per row (no LDS, no barriers); 4 rows per 256-thread block.
__global__ __launch_bounds__(256)
void softmax_kernel(__bf16* __restrict__ S)
{
    const int wid  = threadIdx.x >> 6;
    const int lane = threadIdx.x & 63;
    const int q    = blockIdx.x * 4 + wid;
    const int b    = blockIdx.y;
    if (q >= N_) return;                      // wave-uniform exit
    __bf16* row = S + ((long)b * NP + q) * SLD;
    float v[24];
    float m = -1e30f;
    #pragma unroll
    for (int j = 0; j < 3; ++j) {
        const int k0 = j * 512 + lane * 8;
        bf16x8_t raw = *(const bf16x8_t*)(row + k0);
        #pragma unroll
        for (int i = 0; i < 8; ++i) {
            const float x = (k0 + i < N_) ? bf2f(raw[i]) : -1e30f;
            v[j * 8 + i] = x; m = fmaxf(m, x);
        }
    }
    #pragma unroll
    for (int o = 32; o; o >>= 1) m = fmaxf(m, __shfl_xor(m, o));
    float s = 0.f;
    #pragma unroll
    for (int j = 0; j < 3; ++j) {
        const int k0 = j * 512 + lane * 8;
        #pragma unroll
        for (int i = 0; i < 8; ++i) {
            if (k0 + i < N_) { const float e = __expf(v[j * 8 + i] - m); v[j * 8 + i] = e; s += e; }
            else             v[j * 8 + i] = 0.f;
        }
    }
    #pragma unroll
    for (int o = 32; o; o >>= 1) s += __shfl_xor(s, o);
    const float inv = 1.f / s;
    #pragma unroll
    for (int j = 0; j < 3; ++j) {
        const int k0 = j * 512 + lane * 8;
        bf16x8_t o8;
        #pragma unroll
        for (int i = 0; i < 8; ++i) o8[i] = f2bf(v[j * 8 + i] * inv);
        *(bf16x8_t*)(row + k0) = o8;
    }
}

// --------------------- weighted column sums over attn (q-chunked + atomic)
// lanes t<192 each own 8 columns (bf16x8 row-coalesced loads).
template<int WEIGHTED>
__global__ __launch_bounds__(256)
void colsum_kernel(const __bf16* __restrict__ attn, const float* __restrict__ wv,
                   float* __restrict__ out)
{
    const int t = threadIdx.x;
    if (t >= 192) return;
    const int b  = blockIdx.y;
    const int q0 = blockIdx.x * 16;
    const int q1 = (q0 + 16 < N_) ? q0 + 16 : N_;
    const int k8 = t * 8;
    float s[8] = {};
    const __bf16* base = attn + (long)b * NP * SLD + k8;
    for (int q = q0; q < q1; ++q) {
        bf16x8_t v = *(const bf16x8_t*)(base + (long)q * SLD);
        const float wq = WEIGHTED ? wv[b * NP + q] : 1.0f;
        #pragma unroll
        for (int i = 0; i < 8; ++i) s[i] += wq * bf2f(v[i]);
    }
    #pragma unroll
    for (int i = 0; i < 8; ++i) atomicAdd(out + b * NP + k8 + i, s[i]);
}

// ------------------- pa -> normalize -> curiosity modulation -> fa (output)
// var(pa) dominated by center-bias variance (~5e-3 >> 1e-6): branch 1 only.
__global__ __launch_bounds__(256)
void fa_kernel(const float* __restrict__ pa_raw, const float* __restrict__ curiosity,
               const float* __restrict__ Wc1, const float* __restrict__ bc1,
               const float* __restrict__ Wc2, const float* __restrict__ bc2,
               const float* __restrict__ aw_p,
               float* __restrict__ fa_ws, float* __restrict__ out_fa)
{
    const int b = blockIdx.x, t = threadIdx.x;
    __shared__ float hsh[64];
    __shared__ float red[8];
    __shared__ float cwsh;
    if (t < 64) hsh[t] = fmaxf(0.f, curiosity[b] * Wc1[t] + bc1[t]);
    __syncthreads();
    if (t < 8) {
        float a = bc2[t];
        for (int j = 0; j < 64; ++j) a += hsh[j] * Wc2[j * 8 + t];
        red[t] = 1.f / (1.f + __expf(-a));
    }
    __syncthreads();
    if (t == 0) {
        float cw = 0.f;
        for (int i = 0; i < 8; ++i) cw += red[i];
        cwsh = cw * 0.125f;
    }
    __syncthreads();
    const float aw   = aw_p[0];
    const float modf = 1.f + aw * cwsh;
    const float sig  = 37.f / 6.f;
    const float inv2s2 = 1.f / (2.f * sig * sig);
    float pv[6];
    float s1 = 0.f;
    #pragma unroll
    for (int i = 0; i < 6; ++i) {
        const int k = t + i * 256;
        float p = 0.f;
        if (k < N_) {
            const int y = k / 37, x = k - y * 37;
            const float d2 = (float)((x - 18) * (x - 18) + (y - 18) * (y - 18));
            const float cb = 0.3f * __expf(-d2 * inv2s2);
            p = pa_raw[b * NP + k] * (1.f / 1369.f) + cb;
        }
        pv[i] = p; s1 += p;
    }
    #pragma unroll
    for (int o = 32; o; o >>= 1) s1 += __shfl_xor(s1, o);
    __syncthreads();
    if (!(t & 63)) red[t >> 6] = s1;
    __syncthreads();
    s1 = red[0] + red[1] + red[2] + red[3];
    const float inv1 = 1.f / (s1 + 1e-8f);
    float s2 = 0.f;
    #pragma unroll
    for (int i = 0; i < 6; ++i) {
        const int k = t + i * 256;
        if (k < N_) {
            const float f = fmaxf(pv[i] * inv1 * modf, 1e-8f);
            pv[i] = f; s2 += f;
        }
    }
    #pragma unroll
    for (int o = 32; o; o >>= 1) s2 += __shfl_xor(s2, o);
    if (!(t & 63)) red[4 + (t >> 6)] = s2;
    __syncthreads();
    s2 = red[4] + red[5] + red[6] + red[7];
    const float inv2 = 1.f / (s2 + 1e-8f);
    #pragma unroll
    for (int i = 0; i < 6; ++i) {
        const int k = t + i * 256;
        if (k < N_) {
            const float f = pv[i] * inv2;
            fa_ws[b * NP + k]  = f;
            out_fa[b * N_ + k] = f;
        }
    }
}

// ------------------------------------- weighted[b,d] = sum_k g[b,k]*V[b,k,d]
__global__ __launch_bounds__(256)
void weighted_kernel(const float* __restrict__ g, const __bf16* __restrict__ V,
                     int ldv, float* __restrict__ wout)
{
    const int b  = blockIdx.y;
    const int k0 = blockIdx.x * 86;
    const int k1 = (k0 + 86 < N_) ? k0 + 86 : N_;
    const int d  = threadIdx.x * 4;
    float a0 = 0, a1 = 0, a2 = 0, a3 = 0;
    const __bf16* vb = V + (long)b * NP * ldv + d;
    for (int k = k0; k < k1; ++k) {
        const float gv = g[b * NP + k];
        bf16x4_t vv = *(const bf16x4_t*)(vb + (long)k * ldv);
        a0 += gv * bf2f(vv[0]); a1 += gv * bf2f(vv[1]);
        a2 += gv * bf2f(vv[2]); a3 += gv * bf2f(vv[3]);
    }
    atomicAdd(wout + b * D_ + d + 0, a0);
    atomicAdd(wout + b * D_ + d + 1, a1);
    atomicAdd(wout + b * D_ + d + 2, a2);
    atomicAdd(wout + b * D_ + d + 3, a3);
}

// -------------------------- focal = relu(weighted@Wp1+bp1)@Wp2+bp2  (fp32)
__global__ __launch_bounds__(256)
void focal_kernel(const float* __restrict__ weighted, const float* __restrict__ Wp1,
                  const float* __restrict__ bp1, const float* __restrict__ Wp2,
                  const float* __restrict__ bp2, float* __restrict__ out)
{
    const int b = blockIdx.x, t = threadIdx.x;
    __shared__ float wsh[1024];
    __shared__ float hsh[512];
    for (int i = t; i < 1024; i += 256) wsh[i] = weighted[b * 1024 + i];
    __syncthreads();
    for (int j = t; j < 512; j += 256) {
        float a = bp1[j];
        for (int d2 = 0; d2 < 1024; ++d2) a += wsh[d2] * Wp1[d2 * 512 + j];
        hsh[j] = fmaxf(a, 0.f);
    }
    __syncthreads();
    for (int o = t; o < 128; o += 256) {
        float a = bp2[o];
        for (int j = 0; j < 512; ++j) a += hsh[j] * Wp2[j * 128 + o];
        out[b * 128 + o] = a;
    }
}

// ---------------------------------------------------------------- launcher
extern "C" void kernel_launch(void* const* d_in, const int* in_sizes, int n_in,
                              void* d_out, int out_size, void* d_ws, size_t ws_size,
                              hipStream_t stream)
{
    const float* patch     = (const float*)d_in[0];
    const float* curiosity = (const float*)d_in[1];
    const float* Wq  = (const float*)d_in[2];
    const float* bq  = (const float*)d_in[3];
    const float* Wk  = (const float*)d_in[4];
    const float* bk  = (const float*)d_in[5];
    const float* Wv  = (const float*)d_in[6];
    const float* bv  = (const float*)d_in[7];
    const float* Wc1 = (const float*)d_in[8];
    const float* bc1 = (const float*)d_in[9];
    const float* Wc2 = (const float*)d_in[10];
    const float* bc2 = (const float*)d_in[11];
    const float* Wp1 = (const float*)d_in[12];
    const float* bp1 = (const float*)d_in[13];
    const float* Wp2 = (const float*)d_in[14];
    const float* bp2 = (const float*)d_in[15];
    const float* aw  = (const float*)d_in[16];
    float* out = (float*)d_out;

    char* ws = (char*)d_ws;
    size_t off = 0;
    auto alloc = [&](size_t bytes) -> char* {
        char* p = ws + off;
        off += (bytes + 255) & ~(size_t)255;
        return p;
    };
    // region 0: {pos, X, WT} -- later aliased by S (all fully rewritten each call)
    float*  pos  = (float*) alloc((size_t)N_ * D_ * 4);                 // 5.6 MB
    __bf16* X    = (__bf16*)alloc((size_t)B_ * NP * D_ * 2);            // 50.3 MB
    __bf16* WT   = (__bf16*)alloc((size_t)3 * D_ * D_ * 2);             // 6.3 MB
    const size_t S_BYTES = (size_t)B_ * NP * SLD * 2;                   // 77.1 MB
    if (off < S_BYTES) off = S_BYTES;
    __bf16* S    = (__bf16*)ws;                                         // alias region 0
    __bf16* QKV  = (__bf16*)alloc((size_t)B_ * NP * QLD * 2);           // 152.6 MB
    float*  pa   = (float*) alloc((size_t)B_ * NP * 4);
    float*  faw  = (float*) alloc((size_t)B_ * NP * 4);
    float*  gbuf = (float*) alloc((size_t)B_ * NP * 4);
    float*  wsum = (float*) alloc((size_t)B_ * D_ * 4);
    float*  bcat = (float*) alloc((size_t)NQKV * 4);

    (void)hipMemsetAsync(pa,   0, (size_t)B_ * NP * 4, stream);
    (void)hipMemsetAsync(gbuf, 0, (size_t)B_ * NP * 4, stream);
    (void)hipMemsetAsync(wsum, 0, (size_t)B_ * D_ * 4, stream);

    pos_kernel<<<(N_ * D_ + 255) / 256, 256, 0, stream>>>(pos);
    addpos_kernel<<<(int)((size_t)B_ * NP * D_ / 4 / 256), 256, 0, stream>>>(patch, pos, X);
    {
        dim3 g(16, 16, 3);
        wcast_kernel<<<g, 256, 0, stream>>>(Wq, Wk, Wv,
                                            WT, WT + D_ * D_, WT + 2 * D_ * D_);
    }
    bcat_kernel<<<(NQKV + 255) / 256, 256, 0, stream>>>(bq, bk, bv, bcat);
    {
        // QKV projection: M=B*NP=24576(96), N=3072(12), K=1024 -> 1152 blocks
        const int nwg = 96 * 12;
        gemm256<1><<<nwg, 512, 0, stream>>>(X, WT, QKV, bcat,
                                            D_, D_, QLD, D_, 1.0f,
                                            0, 0, 0, 12, nwg, nwg / 8);
    }
    {
        // scores: per batch M=N=1536(6x6), K=1024; 16 batches -> 576 blocks
        const int nwg = 36 * B_;
        gemm256<0><<<nwg, 512, 0, stream>>>(QKV, QKV + D_, S, nullptr,
                                            QLD, QLD, SLD, D_,
                                            0.08838834764831845f,
                                            (long)NP * QLD, (long)NP * QLD,
                                            (long)NP * SLD, 6, 36, nwg / 8);
    }
    {
        dim3 g((N_ + 3) / 4, B_);
        softmax_kernel<<<g, 256, 0, stream>>>(S);
    }
    {
        dim3 g(86, B_);
        colsum_kernel<0><<<g, 256, 0, stream>>>(S, nullptr, pa);
    }
    fa_kernel<<<B_, 256, 0, stream>>>(pa, curiosity, Wc1, bc1, Wc2, bc2, aw,
                                      faw, out + B_ * 128);
    {
        dim3 g(86, B_);
        colsum_kernel<1><<<g, 256, 0, stream>>>(S, faw, gbuf);
    }
    {
        dim3 g(16, B_);
        weighted_kernel<<<g, 256, 0, stream>>>(gbuf, QKV + 2 * D_, QLD, wsum);
    }
    focal_kernel<<<B_, 256, 0, stream>>>(wsum, Wp1, bp1, Wp2, bp2, out);
}

// Round 5
// 562.184 us; speedup vs baseline: 1.0991x; 1.0664x over previous
//
#include <hip/hip_runtime.h>
#include <hip/hip_bf16.h>
#include <cstdint>

#define B_   16
#define N_   1369
#define NP   1536
#define D_   1024
#define NQKV 3072
#define SLD  1568   // S leading dim (3136B rows: odd multiple of 64B)
#define QLD  3104   // QKV leading dim (6208B rows)

typedef __bf16 bf16x8_t __attribute__((ext_vector_type(8)));
typedef __bf16 bf16x4_t __attribute__((ext_vector_type(4)));
typedef float  f32x4_t  __attribute__((ext_vector_type(4)));

__device__ __forceinline__ float  bf2f(__bf16 x) { return (float)x; }
__device__ __forceinline__ __bf16 f2bf(float x)  { return (__bf16)x; }

#define GLOAD_LDS16(g, l) __builtin_amdgcn_global_load_lds( \
    (const __attribute__((address_space(1))) void*)(g),     \
    (__attribute__((address_space(3))) void*)(l), 16, 0, 0)

// ---------------------------------------------------------------- pos table
__global__ __launch_bounds__(256)
void pos_kernel(float* __restrict__ pos)
{
    const int idx = blockIdx.x * 256 + threadIdx.x;
    if (idx >= N_ * D_) return;
    const int n = idx >> 10, f = idx & 1023;
    const int row = n / 37, col = n - row * 37;
    const float base = (f < 512) ? (float)row : (float)col;
    const int  t2   = (f & 511) >> 1;
    const float dv  = __expf(-0.03597789207803197f * (float)t2);
    const float ang = base * dv;
    pos[idx] = (f & 1) ? cosf(ang) : sinf(ang);
}

// ----------------------------------------------- x = patch + pos, cast bf16
__global__ __launch_bounds__(256)
void addpos_kernel(const float* __restrict__ patch, const float* __restrict__ pos,
                   __bf16* __restrict__ X)
{
    const long tid = (long)blockIdx.x * 256 + threadIdx.x;
    const long e   = tid * 4;
    const int  f   = (int)(e & 1023);
    const long nb  = e >> 10;
    const int  n   = (int)(nb % NP);
    const long b   = nb / NP;
    bf16x4_t o;
    if (n < N_) {
        const float4 p = *(const float4*)(patch + ((b * N_ + n) << 10) + f);
        const float4 q = *(const float4*)(pos + ((long)n << 10) + f);
        o[0] = f2bf(p.x + q.x); o[1] = f2bf(p.y + q.y);
        o[2] = f2bf(p.z + q.z); o[3] = f2bf(p.w + q.w);
    } else {
        o[0] = o[1] = o[2] = o[3] = f2bf(0.f);
    }
    *(bf16x4_t*)(X + e) = o;
}

// ------------------------------------ W[i][o] -> WT[o][i] bf16 (3 matrices)
__global__ __launch_bounds__(256)
void wcast_kernel(const float* __restrict__ W0, const float* __restrict__ W1,
                  const float* __restrict__ W2,
                  __bf16* __restrict__ T0, __bf16* __restrict__ T1, __bf16* __restrict__ T2)
{
    const float* W = blockIdx.z == 0 ? W0 : (blockIdx.z == 1 ? W1 : W2);
    __bf16*      T = blockIdx.z == 0 ? T0 : (blockIdx.z == 1 ? T1 : T2);
    __shared__ float tile[64][65];
    const int o0 = blockIdx.x * 64, i0 = blockIdx.y * 64;
    const int t = threadIdx.x;
    const int tr = t >> 4, tc = (t & 15) * 4;
    #pragma unroll
    for (int rr = 0; rr < 64; rr += 16) {
        float4 v = *(const float4*)(W + (long)(i0 + rr + tr) * 1024 + o0 + tc);
        tile[rr + tr][tc + 0] = v.x; tile[rr + tr][tc + 1] = v.y;
        tile[rr + tr][tc + 2] = v.z; tile[rr + tr][tc + 3] = v.w;
    }
    __syncthreads();
    #pragma unroll
    for (int rr = 0; rr < 64; rr += 16) {
        bf16x4_t o;
        o[0] = f2bf(tile[tc + 0][rr + tr]); o[1] = f2bf(tile[tc + 1][rr + tr]);
        o[2] = f2bf(tile[tc + 2][rr + tr]); o[3] = f2bf(tile[tc + 3][rr + tr]);
        *(bf16x4_t*)(T + (long)(o0 + rr + tr) * 1024 + i0 + tc) = o;
    }
}

// ---------------------------------------------- bias concat [bq|bk|bv] 3072
__global__ __launch_bounds__(256)
void bcat_kernel(const float* __restrict__ bq, const float* __restrict__ bk,
                 const float* __restrict__ bv, float* __restrict__ bcat)
{
    const int i = blockIdx.x * 256 + threadIdx.x;
    if (i >= NQKV) return;
    const int p = i >> 10, j = i & 1023;
    bcat[i] = p == 0 ? bq[j] : (p == 1 ? bk[j] : bv[j]);
}

// ------------------------------------------------------- 256^2 4-phase GEMM
// r2 schedule + SOFTWARE-PIPELINED LDS reads:
//  - A-frags double-buffered (aX/aY): phase p issues reads for p+1, computes on
//    regs read at p-1 -> ds_read issue overlaps MFMA across waves.
//  - B(t) + A(t,p0) read as a 12-read batch at loop top (after P3's
//    vmcnt(4)+barrier -> all waves' gloads landed; cross-wave safe).
//  - staging ledger/vmcnt(4) identical to r2 (proven).
template<int HAS_BIAS>
__global__ __launch_bounds__(512, 2)
void gemm256(const __bf16* __restrict__ A, const __bf16* __restrict__ Bt,
             __bf16* __restrict__ C, const float* __restrict__ bias,
             int lda, int ldb, int ldc, int Kd, float scale,
             long sA, long sB, long sC, int tilesN, int tilesPerBatch, int cpx)
{
    __shared__ __bf16 lds[65536];   // 128 KiB
    const int bid = blockIdx.x;
    const int vt  = (bid & 7) * cpx + (bid >> 3);      // XCD-bijective (nwg%8==0)
    const int bz  = vt / tilesPerBatch;
    const int rem = vt - bz * tilesPerBatch;
    const int ty  = rem / tilesN;
    const int tx  = rem - ty * tilesN;
    A  += (long)bz * sA;  Bt += (long)bz * sB;  C += (long)bz * sC;
    const int m0 = ty * 256, n0 = tx * 256;

    const int t  = threadIdx.x;
    const int w  = t >> 6, l = t & 63;
    const int wr = w >> 2, wc = w & 3;         // 2 x 4 wave grid
    const int lr = l & 15, lh = l >> 4;

    const int laneF  = (lr * 64 + ((lh * 16) ^ (((lr >> 3) & 1) << 5))) >> 1;
    const int rstage = w * 16 + (l >> 2);
    const int kstage = ((l & 3) * 8) ^ (((l >> 5) & 1) << 4);

    const __bf16* Ag = A  + (long)(m0 + rstage) * lda + kstage;
    const __bf16* Bg = Bt + (long)(n0 + rstage) * ldb + kstage;
    __bf16* dA = lds + w * 1024;
    __bf16* dB = lds + 16384 + w * 1024;

#define SA_(buf, half, kt) do {                                       \
    const __bf16* g_ = Ag + (long)(half) * 128 * lda + (kt) * 64;     \
    __bf16* d_ = dA + (buf) * 32768 + (half) * 8192;                  \
    GLOAD_LDS16(g_, d_); GLOAD_LDS16(g_ + 32, d_ + 512); } while (0)
#define SB_(buf, half, kt) do {                                       \
    const __bf16* g_ = Bg + (long)(half) * 128 * ldb + (kt) * 64;     \
    __bf16* d_ = dB + (buf) * 32768 + (half) * 8192;                  \
    GLOAD_LDS16(g_, d_); GLOAD_LDS16(g_ + 32, d_ + 512); } while (0)

    f32x4_t acc[8][4] = {};
    bf16x8_t bfr[4][2];
    bf16x8_t aX0, aX1, aX2, aX3, aY0, aY1, aY2, aY3;

#define AREAD_(S0,S1,S2,S3, base, p) do {                                    \
    const __bf16* ap_ = lds + (base) + wr * 8192 + (p) * 2048 + laneF;       \
    S0 = *(const bf16x8_t*)(ap_);                                            \
    S1 = *(const bf16x8_t*)(ap_ + 512);                                      \
    S2 = *(const bf16x8_t*)(ap_ + 1024);                                     \
    S3 = *(const bf16x8_t*)(ap_ + 1536); } while (0)

#define BREAD_(base) do { const __bf16* bp_ = lds + (base) + laneF;                        \
    bfr[0][0] = *(const bf16x8_t*)(bp_);        bfr[0][1] = *(const bf16x8_t*)(bp_ + 512); \
    bfr[1][0] = *(const bf16x8_t*)(bp_ + 1024); bfr[1][1] = *(const bf16x8_t*)(bp_ + 1536);\
    bfr[2][0] = *(const bf16x8_t*)(bp_ + 2048); bfr[2][1] = *(const bf16x8_t*)(bp_ + 2560);\
    bfr[3][0] = *(const bf16x8_t*)(bp_ + 3072); bfr[3][1] = *(const bf16x8_t*)(bp_ + 3584);} while (0)

#define MFMAC_(pp, S0,S1,S2,S3) do {                                                   \
    __builtin_amdgcn_s_setprio(1);                                                     \
    _Pragma("unroll") for (int nn = 0; nn < 4; ++nn)                                   \
      acc[(pp)*2+0][nn] = __builtin_amdgcn_mfma_f32_16x16x32_bf16(S0, bfr[nn][0], acc[(pp)*2+0][nn], 0, 0, 0); \
    _Pragma("unroll") for (int nn = 0; nn < 4; ++nn)                                   \
      acc[(pp)*2+1][nn] = __builtin_amdgcn_mfma_f32_16x16x32_bf16(S2, bfr[nn][0], acc[(pp)*2+1][nn], 0, 0, 0); \
    _Pragma("unroll") for (int nn = 0; nn < 4; ++nn)                                   \
      acc[(pp)*2+0][nn] = __builtin_amdgcn_mfma_f32_16x16x32_bf16(S1, bfr[nn][1], acc[(pp)*2+0][nn], 0, 0, 0); \
    _Pragma("unroll") for (int nn = 0; nn < 4; ++nn)                                   \
      acc[(pp)*2+1][nn] = __builtin_amdgcn_mfma_f32_16x16x32_bf16(S3, bfr[nn][1], acc[(pp)*2+1][nn], 0, 0, 0); \
    __builtin_amdgcn_s_setprio(0); } while (0)

#define SBAR_ __builtin_amdgcn_sched_barrier(0)
#define BAR_  __builtin_amdgcn_s_barrier()

    const int NT = Kd >> 6;
    // prologue: tile0 fully + tile1 B halves in flight
    SA_(0, 0, 0); SA_(0, 1, 0); SB_(0, 0, 0); SB_(0, 1, 0);
    SB_(1, 0, 1); SB_(1, 1, 1);
    asm volatile("s_waitcnt vmcnt(4)" ::: "memory");
    BAR_;

    for (int tk = 0; tk < NT; ++tk) {
        const int c  = tk & 1, o = c ^ 1;
        const int t1 = (tk + 1 < NT) ? tk + 1 : NT - 1;   // clamped dummy at tail
        const int t2 = (tk + 2 < NT) ? tk + 2 : NT - 1;
        const int st = (tk + 2 < NT);
        const int cbase = c * 32768;
        const int cbB   = cbase + 16384 + wc * 4096;
        // loop-top batch: this tile's B (8) + A p0 (4); landed-guaranteed by
        // prev iter's vmcnt(4)+barrier. P0's MFMA waits these via counted lgkm.
        AREAD_(aX0, aX1, aX2, aX3, cbase, 0);
        BREAD_(cbB);
        SBAR_;
        // P0: issue A(p1); compute p0 on aX
        AREAD_(aY0, aY1, aY2, aY3, cbase, 1);
        SA_(o, 0, t1);
        SBAR_; BAR_;
        MFMAC_(0, aX0, aX1, aX2, aX3);
        BAR_;
        // P1: issue A(p2); compute p1 on aY
        AREAD_(aX0, aX1, aX2, aX3, cbase, 2);
        SA_(o, 1, t1);
        SBAR_; BAR_;
        MFMAC_(1, aY0, aY1, aY2, aY3);
        BAR_;
        // P2: issue A(p3); compute p2 on aX
        AREAD_(aY0, aY1, aY2, aY3, cbase, 3);
        SB_(c, 0, t2);
        SBAR_; BAR_;
        MFMAC_(2, aX0, aX1, aX2, aX3);
        BAR_;
        // P3: compute p3 on aY; vmcnt before barrier
        SB_(c, 1, t2);
        SBAR_; BAR_;
        MFMAC_(3, aY0, aY1, aY2, aY3);
        if (st) { asm volatile("s_waitcnt vmcnt(4)" ::: "memory"); }
        else    { asm volatile("s_waitcnt vmcnt(0)" ::: "memory"); }
        BAR_;
    }

    // epilogue: C/D layout col=lane&15, row=(lane>>4)*4+reg
    #pragma unroll
    for (int mi = 0; mi < 8; ++mi) {
        const int row = m0 + wr * 128 + mi * 16 + lh * 4;
        #pragma unroll
        for (int nn = 0; nn < 4; ++nn) {
            const int col = n0 + wc * 64 + nn * 16 + lr;
            const float bb = HAS_BIAS ? bias[col] : 0.0f;
            #pragma unroll
            for (int q = 0; q < 4; ++q)
                C[(long)(row + q) * ldc + col] = f2bf(acc[mi][nn][q] * scale + bb);
        }
    }
#undef SA_
#undef SB_
#undef AREAD_
#undef BREAD_
#undef MFMAC_
#undef SBAR_
#undef BAR_
}

// ------------------------------------------------- row softmax, in place
// one WAVE per row (no LDS, no barriers); 4 rows per 256-thread block.
__global__ __launch_bounds__(256)
void softmax_kernel(__bf16* __restrict__ S)
{
    const int wid  = threadIdx.x >> 6;
    const int lane = threadIdx.x & 63;
    const int q    = blockIdx.x * 4 + wid;
    const int b    = blockIdx.y;
    if (q >= N_) return;                      // wave-uniform exit
    __bf16* row = S + ((long)b * NP + q) * SLD;
    float v[24];
    float m = -1e30f;
    #pragma unroll
    for (int j = 0; j < 3; ++j) {
        const int k0 = j * 512 + lane * 8;
        bf16x8_t raw = *(const bf16x8_t*)(row + k0);
        #pragma unroll
        for (int i = 0; i < 8; ++i) {
            const float x = (k0 + i < N_) ? bf2f(raw[i]) : -1e30f;
            v[j * 8 + i] = x; m = fmaxf(m, x);
        }
    }
    #pragma unroll
    for (int o = 32; o; o >>= 1) m = fmaxf(m, __shfl_xor(m, o));
    float s = 0.f;
    #pragma unroll
    for (int j = 0; j < 3; ++j) {
        const int k0 = j * 512 + lane * 8;
        #pragma unroll
        for (int i = 0; i < 8; ++i) {
            if (k0 + i < N_) { const float e = __expf(v[j * 8 + i] - m); v[j * 8 + i] = e; s += e; }
            else             v[j * 8 + i] = 0.f;
        }
    }
    #pragma unroll
    for (int o = 32; o; o >>= 1) s += __shfl_xor(s, o);
    const float inv = 1.f / s;
    #pragma unroll
    for (int j = 0; j < 3; ++j) {
        const int k0 = j * 512 + lane * 8;
        bf16x8_t o8;
        #pragma unroll
        for (int i = 0; i < 8; ++i) o8[i] = f2bf(v[j * 8 + i] * inv);
        *(bf16x8_t*)(row + k0) = o8;
    }
}

// --------------------- weighted column sums over attn (q-chunked + atomic)
template<int WEIGHTED>
__global__ __launch_bounds__(256)
void colsum_kernel(const __bf16* __restrict__ attn, const float* __restrict__ wv,
                   float* __restrict__ out)
{
    const int t = threadIdx.x;
    if (t >= 192) return;
    const int b  = blockIdx.y;
    const int q0 = blockIdx.x * 16;
    const int q1 = (q0 + 16 < N_) ? q0 + 16 : N_;
    const int k8 = t * 8;
    float s[8] = {};
    const __bf16* base = attn + (long)b * NP * SLD + k8;
    for (int q = q0; q < q1; ++q) {
        bf16x8_t v = *(const bf16x8_t*)(base + (long)q * SLD);
        const float wq = WEIGHTED ? wv[b * NP + q] : 1.0f;
        #pragma unroll
        for (int i = 0; i < 8; ++i) s[i] += wq * bf2f(v[i]);
    }
    #pragma unroll
    for (int i = 0; i < 8; ++i) atomicAdd(out + b * NP + k8 + i, s[i]);
}

// ------------------- pa -> normalize -> curiosity modulation -> fa (output)
__global__ __launch_bounds__(256)
void fa_kernel(const float* __restrict__ pa_raw, const float* __restrict__ curiosity,
               const float* __restrict__ Wc1, const float* __restrict__ bc1,
               const float* __restrict__ Wc2, const float* __restrict__ bc2,
               const float* __restrict__ aw_p,
               float* __restrict__ fa_ws, float* __restrict__ out_fa)
{
    const int b = blockIdx.x, t = threadIdx.x;
    __shared__ float hsh[64];
    __shared__ float red[8];
    __shared__ float cwsh;
    if (t < 64) hsh[t] = fmaxf(0.f, curiosity[b] * Wc1[t] + bc1[t]);
    __syncthreads();
    if (t < 8) {
        float a = bc2[t];
        for (int j = 0; j < 64; ++j) a += hsh[j] * Wc2[j * 8 + t];
        red[t] = 1.f / (1.f + __expf(-a));
    }
    __syncthreads();
    if (t == 0) {
        float cw = 0.f;
        for (int i = 0; i < 8; ++i) cw += red[i];
        cwsh = cw * 0.125f;
    }
    __syncthreads();
    const float aw   = aw_p[0];
    const float modf = 1.f + aw * cwsh;
    const float sig  = 37.f / 6.f;
    const float inv2s2 = 1.f / (2.f * sig * sig);
    float pv[6];
    float s1 = 0.f;
    #pragma unroll
    for (int i = 0; i < 6; ++i) {
        const int k = t + i * 256;
        float p = 0.f;
        if (k < N_) {
            const int y = k / 37, x = k - y * 37;
            const float d2 = (float)((x - 18) * (x - 18) + (y - 18) * (y - 18));
            const float cb = 0.3f * __expf(-d2 * inv2s2);
            p = pa_raw[b * NP + k] * (1.f / 1369.f) + cb;
        }
        pv[i] = p; s1 += p;
    }
    #pragma unroll
    for (int o = 32; o; o >>= 1) s1 += __shfl_xor(s1, o);
    __syncthreads();
    if (!(t & 63)) red[t >> 6] = s1;
    __syncthreads();
    s1 = red[0] + red[1] + red[2] + red[3];
    const float inv1 = 1.f / (s1 + 1e-8f);
    float s2 = 0.f;
    #pragma unroll
    for (int i = 0; i < 6; ++i) {
        const int k = t + i * 256;
        if (k < N_) {
            const float f = fmaxf(pv[i] * inv1 * modf, 1e-8f);
            pv[i] = f; s2 += f;
        }
    }
    #pragma unroll
    for (int o = 32; o; o >>= 1) s2 += __shfl_xor(s2, o);
    if (!(t & 63)) red[4 + (t >> 6)] = s2;
    __syncthreads();
    s2 = red[4] + red[5] + red[6] + red[7];
    const float inv2 = 1.f / (s2 + 1e-8f);
    #pragma unroll
    for (int i = 0; i < 6; ++i) {
        const int k = t + i * 256;
        if (k < N_) {
            const float f = pv[i] * inv2;
            fa_ws[b * NP + k]  = f;
            out_fa[b * N_ + k] = f;
        }
    }
}

// ------------------------------------- weighted[b,d] = sum_k g[b,k]*V[b,k,d]
__global__ __launch_bounds__(256)
void weighted_kernel(const float* __restrict__ g, const __bf16* __restrict__ V,
                     int ldv, float* __restrict__ wout)
{
    const int b  = blockIdx.y;
    const int k0 = blockIdx.x * 86;
    const int k1 = (k0 + 86 < N_) ? k0 + 86 : N_;
    const int d  = threadIdx.x * 4;
    float a0 = 0, a1 = 0, a2 = 0, a3 = 0;
    const __bf16* vb = V + (long)b * NP * ldv + d;
    for (int k = k0; k < k1; ++k) {
        const float gv = g[b * NP + k];
        bf16x4_t vv = *(const bf16x4_t*)(vb + (long)k * ldv);
        a0 += gv * bf2f(vv[0]); a1 += gv * bf2f(vv[1]);
        a2 += gv * bf2f(vv[2]); a3 += gv * bf2f(vv[3]);
    }
    atomicAdd(wout + b * D_ + d + 0, a0);
    atomicAdd(wout + b * D_ + d + 1, a1);
    atomicAdd(wout + b * D_ + d + 2, a2);
    atomicAdd(wout + b * D_ + d + 3, a3);
}

// ---------------- focal stage 1: h[b][j] = relu(weighted@Wp1+bp1), split-K
// grid (8 j-chunks, 16 b): 128 blocks; thread = (j_local*4 + part); each part
// sums 256 d's, 2-step shfl reduce within wave.
__global__ __launch_bounds__(256)
void focal1_kernel(const float* __restrict__ weighted, const float* __restrict__ Wp1,
                   const float* __restrict__ bp1, float* __restrict__ h)
{
    const int b = blockIdx.y, jc = blockIdx.x;
    const int t = threadIdx.x;
    const int jl = t >> 2, part = t & 3;
    const int j = jc * 64 + jl;
    const float* wb = weighted + b * 1024 + part * 256;
    const float* wp = Wp1 + (long)(part * 256) * 512 + j;
    float a = 0.f;
    #pragma unroll 8
    for (int d = 0; d < 256; ++d) a += wb[d] * wp[(long)d * 512];
    a += __shfl_xor(a, 1);
    a += __shfl_xor(a, 2);
    if (part == 0) h[b * 512 + j] = fmaxf(a + bp1[j], 0.f);
}

// ---------------- focal stage 2: out = h@Wp2 + bp2 (coalesced Wp2 rows)
__global__ __launch_bounds__(128)
void focal2_kernel(const float* __restrict__ h, const float* __restrict__ Wp2,
                   const float* __restrict__ bp2, float* __restrict__ out)
{
    const int b = blockIdx.x, o = threadIdx.x;
    __shared__ float hs[512];
    for (int i = o; i < 512; i += 128) hs[i] = h[b * 512 + i];
    __syncthreads();
    float a = bp2[o];
    #pragma unroll 8
    for (int j = 0; j < 512; ++j) a += hs[j] * Wp2[j * 128 + o];
    out[b * 128 + o] = a;
}

// ---------------------------------------------------------------- launcher
extern "C" void kernel_launch(void* const* d_in, const int* in_sizes, int n_in,
                              void* d_out, int out_size, void* d_ws, size_t ws_size,
                              hipStream_t stream)
{
    const float* patch     = (const float*)d_in[0];
    const float* curiosity = (const float*)d_in[1];
    const float* Wq  = (const float*)d_in[2];
    const float* bq  = (const float*)d_in[3];
    const float* Wk  = (const float*)d_in[4];
    const float* bk  = (const float*)d_in[5];
    const float* Wv  = (const float*)d_in[6];
    const float* bv  = (const float*)d_in[7];
    const float* Wc1 = (const float*)d_in[8];
    const float* bc1 = (const float*)d_in[9];
    const float* Wc2 = (const float*)d_in[10];
    const float* bc2 = (const float*)d_in[11];
    const float* Wp1 = (const float*)d_in[12];
    const float* bp1 = (const float*)d_in[13];
    const float* Wp2 = (const float*)d_in[14];
    const float* bp2 = (const float*)d_in[15];
    const float* aw  = (const float*)d_in[16];
    float* out = (float*)d_out;

    char* ws = (char*)d_ws;
    size_t off = 0;
    auto alloc = [&](size_t bytes) -> char* {
        char* p = ws + off;
        off += (bytes + 255) & ~(size_t)255;
        return p;
    };
    // region 0: {pos, X, WT} -- later aliased by S (all fully rewritten each call)
    float*  pos  = (float*) alloc((size_t)N_ * D_ * 4);
    __bf16* X    = (__bf16*)alloc((size_t)B_ * NP * D_ * 2);
    __bf16* WT   = (__bf16*)alloc((size_t)3 * D_ * D_ * 2);
    const size_t S_BYTES = (size_t)B_ * NP * SLD * 2;
    if (off < S_BYTES) off = S_BYTES;
    __bf16* S    = (__bf16*)ws;                                         // alias region 0
    __bf16* QKV  = (__bf16*)alloc((size_t)B_ * NP * QLD * 2);
    float*  pa   = (float*) alloc((size_t)B_ * NP * 4);
    float*  faw  = (float*) alloc((size_t)B_ * NP * 4);
    float*  gbuf = (float*) alloc((size_t)B_ * NP * 4);
    float*  wsum = (float*) alloc((size_t)B_ * D_ * 4);
    float*  bcat = (float*) alloc((size_t)NQKV * 4);
    float*  hbuf = (float*) alloc((size_t)B_ * 512 * 4);

    (void)hipMemsetAsync(pa,   0, (size_t)B_ * NP * 4, stream);
    (void)hipMemsetAsync(gbuf, 0, (size_t)B_ * NP * 4, stream);
    (void)hipMemsetAsync(wsum, 0, (size_t)B_ * D_ * 4, stream);

    pos_kernel<<<(N_ * D_ + 255) / 256, 256, 0, stream>>>(pos);
    addpos_kernel<<<(int)((size_t)B_ * NP * D_ / 4 / 256), 256, 0, stream>>>(patch, pos, X);
    {
        dim3 g(16, 16, 3);
        wcast_kernel<<<g, 256, 0, stream>>>(Wq, Wk, Wv,
                                            WT, WT + D_ * D_, WT + 2 * D_ * D_);
    }
    bcat_kernel<<<(NQKV + 255) / 256, 256, 0, stream>>>(bq, bk, bv, bcat);
    {
        // QKV projection: M=B*NP=24576(96), N=3072(12), K=1024 -> 1152 blocks
        const int nwg = 96 * 12;
        gemm256<1><<<nwg, 512, 0, stream>>>(X, WT, QKV, bcat,
                                            D_, D_, QLD, D_, 1.0f,
                                            0, 0, 0, 12, nwg, nwg / 8);
    }
    {
        // scores: per batch M=N=1536(6x6), K=1024; 16 batches -> 576 blocks
        const int nwg = 36 * B_;
        gemm256<0><<<nwg, 512, 0, stream>>>(QKV, QKV + D_, S, nullptr,
                                            QLD, QLD, SLD, D_,
                                            0.08838834764831845f,
                                            (long)NP * QLD, (long)NP * QLD,
                                            (long)NP * SLD, 6, 36, nwg / 8);
    }
    {
        dim3 g((N_ + 3) / 4, B_);
        softmax_kernel<<<g, 256, 0, stream>>>(S);
    }
    {
        dim3 g(86, B_);
        colsum_kernel<0><<<g, 256, 0, stream>>>(S, nullptr, pa);
    }
    fa_kernel<<<B_, 256, 0, stream>>>(pa, curiosity, Wc1, bc1, Wc2, bc2, aw,
                                      faw, out + B_ * 128);
    {
        dim3 g(86, B_);
        colsum_kernel<1><<<g, 256, 0, stream>>>(S, faw, gbuf);
    }
    {
        dim3 g(16, B_);
        weighted_kernel<<<g, 256, 0, stream>>>(gbuf, QKV + 2 * D_, QLD, wsum);
    }
    {
        dim3 g(8, B_);
        focal1_kernel<<<g, 256, 0, stream>>>(wsum, Wp1, bp1, hbuf);
    }
    focal2_kernel<<<B_, 128, 0, stream>>>(hbuf, Wp2, bp2, out);
}

// Round 6
// 560.351 us; speedup vs baseline: 1.1027x; 1.0033x over previous
//
#include <hip/hip_runtime.h>
#include <hip/hip_bf16.h>
#include <cstdint>

#define B_   16
#define N_   1369
#define NP   1536
#define D_   1024
#define NQKV 3072
#define SLD  1568   // S leading dim (3136B rows: odd multiple of 64B)
#define QLD  3104   // QKV leading dim (6208B rows)

typedef __bf16 bf16x8_t __attribute__((ext_vector_type(8)));
typedef __bf16 bf16x4_t __attribute__((ext_vector_type(4)));
typedef float  f32x4_t  __attribute__((ext_vector_type(4)));

__device__ __forceinline__ float  bf2f(__bf16 x) { return (float)x; }
__device__ __forceinline__ __bf16 f2bf(float x)  { return (__bf16)x; }

#define GLOAD_LDS16(g, l) __builtin_amdgcn_global_load_lds( \
    (const __attribute__((address_space(1))) void*)(g),     \
    (__attribute__((address_space(3))) void*)(l), 16, 0, 0)

// ---------------------------------------------------------------- pos table
__global__ __launch_bounds__(256)
void pos_kernel(float* __restrict__ pos)
{
    const int idx = blockIdx.x * 256 + threadIdx.x;
    if (idx >= N_ * D_) return;
    const int n = idx >> 10, f = idx & 1023;
    const int row = n / 37, col = n - row * 37;
    const float base = (f < 512) ? (float)row : (float)col;
    const int  t2   = (f & 511) >> 1;
    const float dv  = __expf(-0.03597789207803197f * (float)t2);
    const float ang = base * dv;
    pos[idx] = (f & 1) ? cosf(ang) : sinf(ang);
}

// ----------------------------------------------- x = patch + pos, cast bf16
__global__ __launch_bounds__(256)
void addpos_kernel(const float* __restrict__ patch, const float* __restrict__ pos,
                   __bf16* __restrict__ X)
{
    const long tid = (long)blockIdx.x * 256 + threadIdx.x;
    const long e   = tid * 4;
    const int  f   = (int)(e & 1023);
    const long nb  = e >> 10;
    const int  n   = (int)(nb % NP);
    const long b   = nb / NP;
    bf16x4_t o;
    if (n < N_) {
        const float4 p = *(const float4*)(patch + ((b * N_ + n) << 10) + f);
        const float4 q = *(const float4*)(pos + ((long)n << 10) + f);
        o[0] = f2bf(p.x + q.x); o[1] = f2bf(p.y + q.y);
        o[2] = f2bf(p.z + q.z); o[3] = f2bf(p.w + q.w);
    } else {
        o[0] = o[1] = o[2] = o[3] = f2bf(0.f);
    }
    *(bf16x4_t*)(X + e) = o;
}

// ------------------------------------ W[i][o] -> WT[o][i] bf16 (3 matrices)
__global__ __launch_bounds__(256)
void wcast_kernel(const float* __restrict__ W0, const float* __restrict__ W1,
                  const float* __restrict__ W2,
                  __bf16* __restrict__ T0, __bf16* __restrict__ T1, __bf16* __restrict__ T2)
{
    const float* W = blockIdx.z == 0 ? W0 : (blockIdx.z == 1 ? W1 : W2);
    __bf16*      T = blockIdx.z == 0 ? T0 : (blockIdx.z == 1 ? T1 : T2);
    __shared__ float tile[64][65];
    const int o0 = blockIdx.x * 64, i0 = blockIdx.y * 64;
    const int t = threadIdx.x;
    const int tr = t >> 4, tc = (t & 15) * 4;
    #pragma unroll
    for (int rr = 0; rr < 64; rr += 16) {
        float4 v = *(const float4*)(W + (long)(i0 + rr + tr) * 1024 + o0 + tc);
        tile[rr + tr][tc + 0] = v.x; tile[rr + tr][tc + 1] = v.y;
        tile[rr + tr][tc + 2] = v.z; tile[rr + tr][tc + 3] = v.w;
    }
    __syncthreads();
    #pragma unroll
    for (int rr = 0; rr < 64; rr += 16) {
        bf16x4_t o;
        o[0] = f2bf(tile[tc + 0][rr + tr]); o[1] = f2bf(tile[tc + 1][rr + tr]);
        o[2] = f2bf(tile[tc + 2][rr + tr]); o[3] = f2bf(tile[tc + 3][rr + tr]);
        *(bf16x4_t*)(T + (long)(o0 + rr + tr) * 1024 + i0 + tc) = o;
    }
}

// ---------------------------------------------- bias concat [bq|bk|bv] 3072
__global__ __launch_bounds__(256)
void bcat_kernel(const float* __restrict__ bq, const float* __restrict__ bk,
                 const float* __restrict__ bv, float* __restrict__ bcat)
{
    const int i = blockIdx.x * 256 + threadIdx.x;
    if (i >= NQKV) return;
    const int p = i >> 10, j = i & 1023;
    bcat[i] = p == 0 ? bq[j] : (p == 1 ? bk[j] : bv[j]);
}

// --------------------------------------------- 256^2 counted-lgkm GEMM
// Per K-tile: issue ALL 24 ds_read_b128 (B first) + 8 prefetch gloads for
// tile t+1, then 64 MFMA in read order. NO mid-tile barriers, NO explicit
// lgkmcnt -- compiler inserts counted lgkmcnt at first use, so LDS drain
// overlaps the MFMA pipe. One vmcnt(0)+s_barrier per K-tile (prefetch was
// issued a full tile earlier -> cheap). Swizzle identical to r2 (0 conflicts).
template<int HAS_BIAS>
__global__ __launch_bounds__(512, 2)
void gemm256(const __bf16* __restrict__ A, const __bf16* __restrict__ Bt,
             __bf16* __restrict__ C, const float* __restrict__ bias,
             int lda, int ldb, int ldc, int Kd, float scale,
             long sA, long sB, long sC, int tilesN, int tilesPerBatch, int cpx)
{
    __shared__ __bf16 lds[65536];   // 128 KiB: A bufs @0/@32768, B @16384/@49152
    const int bid = blockIdx.x;
    const int vt  = (bid & 7) * cpx + (bid >> 3);      // XCD-bijective (nwg%8==0)
    const int bz  = vt / tilesPerBatch;
    const int rem = vt - bz * tilesPerBatch;
    const int ty  = rem / tilesN;
    const int tx  = rem - ty * tilesN;
    A  += (long)bz * sA;  Bt += (long)bz * sB;  C += (long)bz * sC;
    const int m0 = ty * 256, n0 = tx * 256;

    const int t  = threadIdx.x;
    const int w  = t >> 6, l = t & 63;
    const int wr = w >> 2, wc = w & 3;         // 2 x 4 wave grid
    const int lr = l & 15, lh = l >> 4;

    // swizzled ds_read lane offset (elems); proven 0-conflict (r2 PMC)
    const int laneF  = (lr * 64 + ((lh * 16) ^ (((lr >> 3) & 1) << 5))) >> 1;
    // staging source mapping (inverse swizzle)
    const int rstage = w * 16 + (l >> 2);
    const int kstage = ((l & 3) * 8) ^ (((l >> 5) & 1) << 4);

    const __bf16* Ag = A  + (long)(m0 + rstage) * lda + kstage;
    const __bf16* Bg = Bt + (long)(n0 + rstage) * ldb + kstage;
    __bf16* dA = lds + w * 1024;
    __bf16* dB = lds + 16384 + w * 1024;

#define SA_(buf, half, kt) do {                                       \
    const __bf16* g_ = Ag + (long)(half) * 128 * lda + (kt) * 64;     \
    __bf16* d_ = dA + (buf) * 32768 + (half) * 8192;                  \
    GLOAD_LDS16(g_, d_); GLOAD_LDS16(g_ + 32, d_ + 512); } while (0)
#define SB_(buf, half, kt) do {                                       \
    const __bf16* g_ = Bg + (long)(half) * 128 * ldb + (kt) * 64;     \
    __bf16* d_ = dB + (buf) * 32768 + (half) * 8192;                  \
    GLOAD_LDS16(g_, d_); GLOAD_LDS16(g_ + 32, d_ + 512); } while (0)

    f32x4_t acc[8][4] = {};

    const int NT = Kd >> 6;
    // prologue: tile0 staged, must land
    SA_(0, 0, 0); SA_(0, 1, 0); SB_(0, 0, 0); SB_(0, 1, 0);
    asm volatile("s_waitcnt vmcnt(0)" ::: "memory");
    __builtin_amdgcn_s_barrier();

    for (int tk = 0; tk < NT; ++tk) {
        const int c = tk & 1, o = c ^ 1;
        const int cbase = c * 32768;
        // prefetch tile t+1 into the other buffer (no race: reads are on c)
        if (tk + 1 < NT) {
            SA_(o, 0, tk + 1); SA_(o, 1, tk + 1);
            SB_(o, 0, tk + 1); SB_(o, 1, tk + 1);
        }
        // issue ALL fragment reads for tile t (B first: first MFMAs need B+A0)
        const __bf16* bp = lds + cbase + 16384 + wc * 4096 + laneF;
        const __bf16* ap = lds + cbase + wr * 8192 + laneF;
        bf16x8_t bf0[4], bf1[4], af0[8], af1[8];
        #pragma unroll
        for (int nn = 0; nn < 4; ++nn) bf0[nn] = *(const bf16x8_t*)(bp + nn * 1024);
        #pragma unroll
        for (int mi = 0; mi < 8; ++mi) af0[mi] = *(const bf16x8_t*)(ap + mi * 1024);
        #pragma unroll
        for (int nn = 0; nn < 4; ++nn) bf1[nn] = *(const bf16x8_t*)(bp + nn * 1024 + 512);
        #pragma unroll
        for (int mi = 0; mi < 8; ++mi) af1[mi] = *(const bf16x8_t*)(ap + mi * 1024 + 512);
        // MFMAs in read order; compiler inserts counted lgkmcnt at first use
        __builtin_amdgcn_s_setprio(1);
        #pragma unroll
        for (int mi = 0; mi < 8; ++mi)
            #pragma unroll
            for (int nn = 0; nn < 4; ++nn)
                acc[mi][nn] = __builtin_amdgcn_mfma_f32_16x16x32_bf16(af0[mi], bf0[nn], acc[mi][nn], 0, 0, 0);
        #pragma unroll
        for (int mi = 0; mi < 8; ++mi)
            #pragma unroll
            for (int nn = 0; nn < 4; ++nn)
                acc[mi][nn] = __builtin_amdgcn_mfma_f32_16x16x32_bf16(af1[mi], bf1[nn], acc[mi][nn], 0, 0, 0);
        __builtin_amdgcn_s_setprio(0);
        // tile boundary: prefetch landed (issued a full tile ago), flip buffers
        asm volatile("s_waitcnt vmcnt(0)" ::: "memory");
        __builtin_amdgcn_s_barrier();
    }

    // epilogue: C/D layout col=lane&15, row=(lane>>4)*4+reg
    #pragma unroll
    for (int mi = 0; mi < 8; ++mi) {
        const int row = m0 + wr * 128 + mi * 16 + lh * 4;
        #pragma unroll
        for (int nn = 0; nn < 4; ++nn) {
            const int col = n0 + wc * 64 + nn * 16 + lr;
            const float bb = HAS_BIAS ? bias[col] : 0.0f;
            #pragma unroll
            for (int q = 0; q < 4; ++q)
                C[(long)(row + q) * ldc + col] = f2bf(acc[mi][nn][q] * scale + bb);
        }
    }
#undef SA_
#undef SB_
}

// ------------------------------------------------- row softmax, in place
// one WAVE per row (no LDS, no barriers); 4 rows per 256-thread block.
__global__ __launch_bounds__(256)
void softmax_kernel(__bf16* __restrict__ S)
{
    const int wid  = threadIdx.x >> 6;
    const int lane = threadIdx.x & 63;
    const int q    = blockIdx.x * 4 + wid;
    const int b    = blockIdx.y;
    if (q >= N_) return;                      // wave-uniform exit
    __bf16* row = S + ((long)b * NP + q) * SLD;
    float v[24];
    float m = -1e30f;
    #pragma unroll
    for (int j = 0; j < 3; ++j) {
        const int k0 = j * 512 + lane * 8;
        bf16x8_t raw = *(const bf16x8_t*)(row + k0);
        #pragma unroll
        for (int i = 0; i < 8; ++i) {
            const float x = (k0 + i < N_) ? bf2f(raw[i]) : -1e30f;
            v[j * 8 + i] = x; m = fmaxf(m, x);
        }
    }
    #pragma unroll
    for (int o = 32; o; o >>= 1) m = fmaxf(m, __shfl_xor(m, o));
    float s = 0.f;
    #pragma unroll
    for (int j = 0; j < 3; ++j) {
        const int k0 = j * 512 + lane * 8;
        #pragma unroll
        for (int i = 0; i < 8; ++i) {
            if (k0 + i < N_) { const float e = __expf(v[j * 8 + i] - m); v[j * 8 + i] = e; s += e; }
            else             v[j * 8 + i] = 0.f;
        }
    }
    #pragma unroll
    for (int o = 32; o; o >>= 1) s += __shfl_xor(s, o);
    const float inv = 1.f / s;
    #pragma unroll
    for (int j = 0; j < 3; ++j) {
        const int k0 = j * 512 + lane * 8;
        bf16x8_t o8;
        #pragma unroll
        for (int i = 0; i < 8; ++i) o8[i] = f2bf(v[j * 8 + i] * inv);
        *(bf16x8_t*)(row + k0) = o8;
    }
}

// --------------------- weighted column sums over attn (q-chunked + atomic)
template<int WEIGHTED>
__global__ __launch_bounds__(256)
void colsum_kernel(const __bf16* __restrict__ attn, const float* __restrict__ wv,
                   float* __restrict__ out)
{
    const int t = threadIdx.x;
    if (t >= 192) return;
    const int b  = blockIdx.y;
    const int q0 = blockIdx.x * 16;
    const int q1 = (q0 + 16 < N_) ? q0 + 16 : N_;
    const int k8 = t * 8;
    float s[8] = {};
    const __bf16* base = attn + (long)b * NP * SLD + k8;
    for (int q = q0; q < q1; ++q) {
        bf16x8_t v = *(const bf16x8_t*)(base + (long)q * SLD);
        const float wq = WEIGHTED ? wv[b * NP + q] : 1.0f;
        #pragma unroll
        for (int i = 0; i < 8; ++i) s[i] += wq * bf2f(v[i]);
    }
    #pragma unroll
    for (int i = 0; i < 8; ++i) atomicAdd(out + b * NP + k8 + i, s[i]);
}

// ------------------- pa -> normalize -> curiosity modulation -> fa (output)
__global__ __launch_bounds__(256)
void fa_kernel(const float* __restrict__ pa_raw, const float* __restrict__ curiosity,
               const float* __restrict__ Wc1, const float* __restrict__ bc1,
               const float* __restrict__ Wc2, const float* __restrict__ bc2,
               const float* __restrict__ aw_p,
               float* __restrict__ fa_ws, float* __restrict__ out_fa)
{
    const int b = blockIdx.x, t = threadIdx.x;
    __shared__ float hsh[64];
    __shared__ float red[8];
    __shared__ float cwsh;
    if (t < 64) hsh[t] = fmaxf(0.f, curiosity[b] * Wc1[t] + bc1[t]);
    __syncthreads();
    if (t < 8) {
        float a = bc2[t];
        for (int j = 0; j < 64; ++j) a += hsh[j] * Wc2[j * 8 + t];
        red[t] = 1.f / (1.f + __expf(-a));
    }
    __syncthreads();
    if (t == 0) {
        float cw = 0.f;
        for (int i = 0; i < 8; ++i) cw += red[i];
        cwsh = cw * 0.125f;
    }
    __syncthreads();
    const float aw   = aw_p[0];
    const float modf = 1.f + aw * cwsh;
    const float sig  = 37.f / 6.f;
    const float inv2s2 = 1.f / (2.f * sig * sig);
    float pv[6];
    float s1 = 0.f;
    #pragma unroll
    for (int i = 0; i < 6; ++i) {
        const int k = t + i * 256;
        float p = 0.f;
        if (k < N_) {
            const int y = k / 37, x = k - y * 37;
            const float d2 = (float)((x - 18) * (x - 18) + (y - 18) * (y - 18));
            const float cb = 0.3f * __expf(-d2 * inv2s2);
            p = pa_raw[b * NP + k] * (1.f / 1369.f) + cb;
        }
        pv[i] = p; s1 += p;
    }
    #pragma unroll
    for (int o = 32; o; o >>= 1) s1 += __shfl_xor(s1, o);
    __syncthreads();
    if (!(t & 63)) red[t >> 6] = s1;
    __syncthreads();
    s1 = red[0] + red[1] + red[2] + red[3];
    const float inv1 = 1.f / (s1 + 1e-8f);
    float s2 = 0.f;
    #pragma unroll
    for (int i = 0; i < 6; ++i) {
        const int k = t + i * 256;
        if (k < N_) {
            const float f = fmaxf(pv[i] * inv1 * modf, 1e-8f);
            pv[i] = f; s2 += f;
        }
    }
    #pragma unroll
    for (int o = 32; o; o >>= 1) s2 += __shfl_xor(s2, o);
    if (!(t & 63)) red[4 + (t >> 6)] = s2;
    __syncthreads();
    s2 = red[4] + red[5] + red[6] + red[7];
    const float inv2 = 1.f / (s2 + 1e-8f);
    #pragma unroll
    for (int i = 0; i < 6; ++i) {
        const int k = t + i * 256;
        if (k < N_) {
            const float f = pv[i] * inv2;
            fa_ws[b * NP + k]  = f;
            out_fa[b * N_ + k] = f;
        }
    }
}

// ------------------------------------- weighted[b,d] = sum_k g[b,k]*V[b,k,d]
__global__ __launch_bounds__(256)
void weighted_kernel(const float* __restrict__ g, const __bf16* __restrict__ V,
                     int ldv, float* __restrict__ wout)
{
    const int b  = blockIdx.y;
    const int k0 = blockIdx.x * 86;
    const int k1 = (k0 + 86 < N_) ? k0 + 86 : N_;
    const int d  = threadIdx.x * 4;
    float a0 = 0, a1 = 0, a2 = 0, a3 = 0;
    const __bf16* vb = V + (long)b * NP * ldv + d;
    for (int k = k0; k < k1; ++k) {
        const float gv = g[b * NP + k];
        bf16x4_t vv = *(const bf16x4_t*)(vb + (long)k * ldv);
        a0 += gv * bf2f(vv[0]); a1 += gv * bf2f(vv[1]);
        a2 += gv * bf2f(vv[2]); a3 += gv * bf2f(vv[3]);
    }
    atomicAdd(wout + b * D_ + d + 0, a0);
    atomicAdd(wout + b * D_ + d + 1, a1);
    atomicAdd(wout + b * D_ + d + 2, a2);
    atomicAdd(wout + b * D_ + d + 3, a3);
}

// ---------------- focal stage 1: h[b][j] = relu(weighted@Wp1+bp1), split-K
__global__ __launch_bounds__(256)
void focal1_kernel(const float* __restrict__ weighted, const float* __restrict__ Wp1,
                   const float* __restrict__ bp1, float* __restrict__ h)
{
    const int b = blockIdx.y, jc = blockIdx.x;
    const int t = threadIdx.x;
    const int jl = t >> 2, part = t & 3;
    const int j = jc * 64 + jl;
    const float* wb = weighted + b * 1024 + part * 256;
    const float* wp = Wp1 + (long)(part * 256) * 512 + j;
    float a = 0.f;
    #pragma unroll 8
    for (int d = 0; d < 256; ++d) a += wb[d] * wp[(long)d * 512];
    a += __shfl_xor(a, 1);
    a += __shfl_xor(a, 2);
    if (part == 0) h[b * 512 + j] = fmaxf(a + bp1[j], 0.f);
}

// ---------------- focal stage 2: out = h@Wp2 + bp2 (coalesced Wp2 rows)
__global__ __launch_bounds__(128)
void focal2_kernel(const float* __restrict__ h, const float* __restrict__ Wp2,
                   const float* __restrict__ bp2, float* __restrict__ out)
{
    const int b = blockIdx.x, o = threadIdx.x;
    __shared__ float hs[512];
    for (int i = o; i < 512; i += 128) hs[i] = h[b * 512 + i];
    __syncthreads();
    float a = bp2[o];
    #pragma unroll 8
    for (int j = 0; j < 512; ++j) a += hs[j] * Wp2[j * 128 + o];
    out[b * 128 + o] = a;
}

// ---------------------------------------------------------------- launcher
extern "C" void kernel_launch(void* const* d_in, const int* in_sizes, int n_in,
                              void* d_out, int out_size, void* d_ws, size_t ws_size,
                              hipStream_t stream)
{
    const float* patch     = (const float*)d_in[0];
    const float* curiosity = (const float*)d_in[1];
    const float* Wq  = (const float*)d_in[2];
    const float* bq  = (const float*)d_in[3];
    const float* Wk  = (const float*)d_in[4];
    const float* bk  = (const float*)d_in[5];
    const float* Wv  = (const float*)d_in[6];
    const float* bv  = (const float*)d_in[7];
    const float* Wc1 = (const float*)d_in[8];
    const float* bc1 = (const float*)d_in[9];
    const float* Wc2 = (const float*)d_in[10];
    const float* bc2 = (const float*)d_in[11];
    const float* Wp1 = (const float*)d_in[12];
    const float* bp1 = (const float*)d_in[13];
    const float* Wp2 = (const float*)d_in[14];
    const float* bp2 = (const float*)d_in[15];
    const float* aw  = (const float*)d_in[16];
    float* out = (float*)d_out;

    char* ws = (char*)d_ws;
    size_t off = 0;
    auto alloc = [&](size_t bytes) -> char* {
        char* p = ws + off;
        off += (bytes + 255) & ~(size_t)255;
        return p;
    };
    // region 0: {pos, X, WT} -- later aliased by S (all fully rewritten each call)
    float*  pos  = (float*) alloc((size_t)N_ * D_ * 4);
    __bf16* X    = (__bf16*)alloc((size_t)B_ * NP * D_ * 2);
    __bf16* WT   = (__bf16*)alloc((size_t)3 * D_ * D_ * 2);
    const size_t S_BYTES = (size_t)B_ * NP * SLD * 2;
    if (off < S_BYTES) off = S_BYTES;
    __bf16* S    = (__bf16*)ws;                                         // alias region 0
    __bf16* QKV  = (__bf16*)alloc((size_t)B_ * NP * QLD * 2);
    float*  pa   = (float*) alloc((size_t)B_ * NP * 4);
    float*  faw  = (float*) alloc((size_t)B_ * NP * 4);
    float*  gbuf = (float*) alloc((size_t)B_ * NP * 4);
    float*  wsum = (float*) alloc((size_t)B_ * D_ * 4);
    float*  bcat = (float*) alloc((size_t)NQKV * 4);
    float*  hbuf = (float*) alloc((size_t)B_ * 512 * 4);

    (void)hipMemsetAsync(pa,   0, (size_t)B_ * NP * 4, stream);
    (void)hipMemsetAsync(gbuf, 0, (size_t)B_ * NP * 4, stream);
    (void)hipMemsetAsync(wsum, 0, (size_t)B_ * D_ * 4, stream);

    pos_kernel<<<(N_ * D_ + 255) / 256, 256, 0, stream>>>(pos);
    addpos_kernel<<<(int)((size_t)B_ * NP * D_ / 4 / 256), 256, 0, stream>>>(patch, pos, X);
    {
        dim3 g(16, 16, 3);
        wcast_kernel<<<g, 256, 0, stream>>>(Wq, Wk, Wv,
                                            WT, WT + D_ * D_, WT + 2 * D_ * D_);
    }
    bcat_kernel<<<(NQKV + 255) / 256, 256, 0, stream>>>(bq, bk, bv, bcat);
    {
        // QKV projection: M=B*NP=24576(96), N=3072(12), K=1024 -> 1152 blocks
        const int nwg = 96 * 12;
        gemm256<1><<<nwg, 512, 0, stream>>>(X, WT, QKV, bcat,
                                            D_, D_, QLD, D_, 1.0f,
                                            0, 0, 0, 12, nwg, nwg / 8);
    }
    {
        // scores: per batch M=N=1536(6x6), K=1024; 16 batches -> 576 blocks
        const int nwg = 36 * B_;
        gemm256<0><<<nwg, 512, 0, stream>>>(QKV, QKV + D_, S, nullptr,
                                            QLD, QLD, SLD, D_,
                                            0.08838834764831845f,
                                            (long)NP * QLD, (long)NP * QLD,
                                            (long)NP * SLD, 6, 36, nwg / 8);
    }
    {
        dim3 g((N_ + 3) / 4, B_);
        softmax_kernel<<<g, 256, 0, stream>>>(S);
    }
    {
        dim3 g(86, B_);
        colsum_kernel<0><<<g, 256, 0, stream>>>(S, nullptr, pa);
    }
    fa_kernel<<<B_, 256, 0, stream>>>(pa, curiosity, Wc1, bc1, Wc2, bc2, aw,
                                      faw, out + B_ * 128);
    {
        dim3 g(86, B_);
        colsum_kernel<1><<<g, 256, 0, stream>>>(S, faw, gbuf);
    }
    {
        dim3 g(16, B_);
        weighted_kernel<<<g, 256, 0, stream>>>(gbuf, QKV + 2 * D_, QLD, wsum);
    }
    {
        dim3 g(8, B_);
        focal1_kernel<<<g, 256, 0, stream>>>(wsum, Wp1, bp1, hbuf);
    }
    focal2_kernel<<<B_, 128, 0, stream>>>(hbuf, Wp2, bp2, out);
}

// Round 8
// 552.729 us; speedup vs baseline: 1.1179x; 1.0138x over previous
//
#include <hip/hip_runtime.h>
#include <hip/hip_bf16.h>
#include <cstdint>

#define B_   16
#define N_   1369
#define NP   1536
#define D_   1024
#define NQKV 3072
#define SLD  1568   // S leading dim (3136B rows: odd multiple of 64B)
#define QLD  3104   // QKV leading dim (6208B rows)

typedef __bf16 bf16x8_t __attribute__((ext_vector_type(8)));
typedef __bf16 bf16x4_t __attribute__((ext_vector_type(4)));
typedef float  f32x4_t  __attribute__((ext_vector_type(4)));

__device__ __forceinline__ float  bf2f(__bf16 x) { return (float)x; }
__device__ __forceinline__ __bf16 f2bf(float x)  { return (__bf16)x; }

#define GLOAD_LDS16(g, l) __builtin_amdgcn_global_load_lds( \
    (const __attribute__((address_space(1))) void*)(g),     \
    (__attribute__((address_space(3))) void*)(l), 16, 0, 0)

// ---------------------------------------------------------------- pos table
__global__ __launch_bounds__(256)
void pos_kernel(float* __restrict__ pos)
{
    const int idx = blockIdx.x * 256 + threadIdx.x;
    if (idx >= N_ * D_) return;
    const int n = idx >> 10, f = idx & 1023;
    const int row = n / 37, col = n - row * 37;
    const float base = (f < 512) ? (float)row : (float)col;
    const int  t2   = (f & 511) >> 1;
    const float dv  = __expf(-0.03597789207803197f * (float)t2);
    const float ang = base * dv;
    pos[idx] = (f & 1) ? cosf(ang) : sinf(ang);
}

// ----------------------------------------------- x = patch + pos, cast bf16
__global__ __launch_bounds__(256)
void addpos_kernel(const float* __restrict__ patch, const float* __restrict__ pos,
                   __bf16* __restrict__ X)
{
    const long tid = (long)blockIdx.x * 256 + threadIdx.x;
    const long e   = tid * 4;
    const int  f   = (int)(e & 1023);
    const long nb  = e >> 10;
    const int  n   = (int)(nb % NP);
    const long b   = nb / NP;
    bf16x4_t o;
    if (n < N_) {
        const float4 p = *(const float4*)(patch + ((b * N_ + n) << 10) + f);
        const float4 q = *(const float4*)(pos + ((long)n << 10) + f);
        o[0] = f2bf(p.x + q.x); o[1] = f2bf(p.y + q.y);
        o[2] = f2bf(p.z + q.z); o[3] = f2bf(p.w + q.w);
    } else {
        o[0] = o[1] = o[2] = o[3] = f2bf(0.f);
    }
    *(bf16x4_t*)(X + e) = o;
}

// ------------------------------------ W[i][o] -> WT[o][i] bf16 (3 matrices)
__global__ __launch_bounds__(256)
void wcast_kernel(const float* __restrict__ W0, const float* __restrict__ W1,
                  const float* __restrict__ W2,
                  __bf16* __restrict__ T0, __bf16* __restrict__ T1, __bf16* __restrict__ T2)
{
    const float* W = blockIdx.z == 0 ? W0 : (blockIdx.z == 1 ? W1 : W2);
    __bf16*      T = blockIdx.z == 0 ? T0 : (blockIdx.z == 1 ? T1 : T2);
    __shared__ float tile[64][65];
    const int o0 = blockIdx.x * 64, i0 = blockIdx.y * 64;
    const int t = threadIdx.x;
    const int tr = t >> 4, tc = (t & 15) * 4;
    #pragma unroll
    for (int rr = 0; rr < 64; rr += 16) {
        float4 v = *(const float4*)(W + (long)(i0 + rr + tr) * 1024 + o0 + tc);
        tile[rr + tr][tc + 0] = v.x; tile[rr + tr][tc + 1] = v.y;
        tile[rr + tr][tc + 2] = v.z; tile[rr + tr][tc + 3] = v.w;
    }
    __syncthreads();
    #pragma unroll
    for (int rr = 0; rr < 64; rr += 16) {
        bf16x4_t o;
        o[0] = f2bf(tile[tc + 0][rr + tr]); o[1] = f2bf(tile[tc + 1][rr + tr]);
        o[2] = f2bf(tile[tc + 2][rr + tr]); o[3] = f2bf(tile[tc + 3][rr + tr]);
        *(bf16x4_t*)(T + (long)(o0 + rr + tr) * 1024 + i0 + tc) = o;
    }
}

// ---------------------------------------------- bias concat [bq|bk|bv] 3072
__global__ __launch_bounds__(256)
void bcat_kernel(const float* __restrict__ bq, const float* __restrict__ bk,
                 const float* __restrict__ bv, float* __restrict__ bcat)
{
    const int i = blockIdx.x * 256 + threadIdx.x;
    if (i >= NQKV) return;
    const int p = i >> 10, j = i & 1023;
    bcat[i] = p == 0 ? bq[j] : (p == 1 ? bk[j] : bv[j]);
}

// ---------------------------------------- 256^2 GEMM, 16 waves (4x4), dbuf
// Per-wave output 64x64 -> acc 64 regs -> 4 waves/SIMD (16 waves/CU, 2x the
// 8-wave variant's occupancy, which r2-r6 showed is the wall).
// LDS geometry (r2-proven, grouped): elem (R,k) at
//   (R>>4)*1024 + (k>>5)*512 + (R&15)*32 + ((k&31) ^ ((R&8)?16:0)).
// 16-wave staging: wave w = {rowgroup w>>1, khalf w&1}; lane l = {row l>>2,
// k (l&3)*8}; source k XORs bit4 when row_local>=8 (l>=32). (r7 bug: this
// mapping was derived against a flat [128][64] layout -- fixed.)
// STATS=1 (scores): epilogue emits masked per-row {max, sum-exp} partials so
// the softmax pass over S (154MB RW) is eliminated.
template<int HAS_BIAS, int STATS>
__global__ __launch_bounds__(1024, 4)
void gemm256(const __bf16* __restrict__ A, const __bf16* __restrict__ Bt,
             __bf16* __restrict__ C, const float* __restrict__ bias,
             float2* __restrict__ mzp,
             int lda, int ldb, int ldc, int Kd, float scale,
             long sA, long sB, long sC, int tilesN, int tilesPerBatch, int cpx)
{
    __shared__ __bf16 lds[65536];   // 128 KiB: buf c at c*32768 (A +0, B +16384)
    const int bid = blockIdx.x;
    const int vt  = (bid & 7) * cpx + (bid >> 3);      // XCD-bijective (nwg%8==0)
    const int bz  = vt / tilesPerBatch;
    const int rem = vt - bz * tilesPerBatch;
    const int ty  = rem / tilesN;
    const int tx  = rem - ty * tilesN;
    A  += (long)bz * sA;  Bt += (long)bz * sB;  C += (long)bz * sC;
    const int m0 = ty * 256, n0 = tx * 256;

    const int t  = threadIdx.x;
    const int w  = t >> 6, l = t & 63;
    const int wr = w >> 2, wc = w & 3;         // 4 x 4 wave grid
    const int lr = l & 15, lh = l >> 4;

    // swizzled ds_read lane offset (elems); identical to proven r2/r6
    const int laneF  = (lr * 64 + ((lh * 16) ^ (((lr >> 3) & 1) << 5))) >> 1;
    // staging (16 waves, 1 gload/half): wave w -> rowgroup w>>1, khalf w&1;
    // lane l -> row_local l>>2, k_local (l&3)*8, swizzle XOR when l>=32.
    const int rstage = (w >> 1) * 16 + (l >> 2);
    const int kstage = (w & 1) * 32 + (((l & 3) * 8) ^ (((l >> 5) & 1) << 4));

    const __bf16* Ag = A  + (long)(m0 + rstage) * lda + kstage;
    const __bf16* Bg = Bt + (long)(n0 + rstage) * ldb + kstage;
    __bf16* dA = lds + w * 512;            // + buf*32768 + half*8192
    __bf16* dB = lds + 16384 + w * 512;

#define SA_(buf, half, kt) GLOAD_LDS16(Ag + (long)(half) * 128 * lda + (kt) * 64, \
                                       dA + (buf) * 32768 + (half) * 8192)
#define SB_(buf, half, kt) GLOAD_LDS16(Bg + (long)(half) * 128 * ldb + (kt) * 64, \
                                       dB + (buf) * 32768 + (half) * 8192)

    f32x4_t acc[4][4] = {};

    const int NT = Kd >> 6;
    // prologue: tile0 staged, must land
    SA_(0, 0, 0); SA_(0, 1, 0); SB_(0, 0, 0); SB_(0, 1, 0);
    asm volatile("s_waitcnt vmcnt(0)" ::: "memory");
    __builtin_amdgcn_s_barrier();

    for (int tk = 0; tk < NT; ++tk) {
        const int c = tk & 1, o = c ^ 1;
        if (tk + 1 < NT) {                 // prefetch t+1 into other buffer
            SA_(o, 0, tk + 1); SA_(o, 1, tk + 1);
            SB_(o, 0, tk + 1); SB_(o, 1, tk + 1);
        }
        const int cb = c * 32768;
        const __bf16* ap = lds + cb + (wr >> 1) * 8192 + (wr & 1) * 4096 + laneF;
        const __bf16* bp = lds + cb + 16384 + (wc >> 1) * 8192 + (wc & 1) * 4096 + laneF;
        bf16x8_t af[4], bfm[4];
        // K-slice 0
        #pragma unroll
        for (int nn = 0; nn < 4; ++nn) bfm[nn] = *(const bf16x8_t*)(bp + nn * 1024);
        #pragma unroll
        for (int mi = 0; mi < 4; ++mi) af[mi]  = *(const bf16x8_t*)(ap + mi * 1024);
        __builtin_amdgcn_s_setprio(1);
        #pragma unroll
        for (int mi = 0; mi < 4; ++mi)
            #pragma unroll
            for (int nn = 0; nn < 4; ++nn)
                acc[mi][nn] = __builtin_amdgcn_mfma_f32_16x16x32_bf16(af[mi], bfm[nn], acc[mi][nn], 0, 0, 0);
        __builtin_amdgcn_s_setprio(0);
        // K-slice 1
        #pragma unroll
        for (int nn = 0; nn < 4; ++nn) bfm[nn] = *(const bf16x8_t*)(bp + nn * 1024 + 512);
        #pragma unroll
        for (int mi = 0; mi < 4; ++mi) af[mi]  = *(const bf16x8_t*)(ap + mi * 1024 + 512);
        __builtin_amdgcn_s_setprio(1);
        #pragma unroll
        for (int mi = 0; mi < 4; ++mi)
            #pragma unroll
            for (int nn = 0; nn < 4; ++nn)
                acc[mi][nn] = __builtin_amdgcn_mfma_f32_16x16x32_bf16(af[mi], bfm[nn], acc[mi][nn], 0, 0, 0);
        __builtin_amdgcn_s_setprio(0);
        asm volatile("s_waitcnt vmcnt(0)" ::: "memory");
        __builtin_amdgcn_s_barrier();
    }

    // epilogue: C/D layout col=lane&15, row=(lane>>4)*4+reg
    #pragma unroll
    for (int mi = 0; mi < 4; ++mi) {
        const int row = m0 + wr * 64 + mi * 16 + lh * 4;
        #pragma unroll
        for (int nn = 0; nn < 4; ++nn) {
            const int col = n0 + wc * 64 + nn * 16 + lr;
            const float bb = HAS_BIAS ? bias[col] : 0.0f;
            #pragma unroll
            for (int q = 0; q < 4; ++q)
                C[(long)(row + q) * ldc + col] = f2bf(acc[mi][nn][q] * scale + bb);
        }
    }

    if (STATS) {
        // per-row (q) masked max & sum-exp partials over this block's 256 cols
        __syncthreads();                      // safe to reuse lds
        float* lm = (float*)lds;              // [256][4]
        float* lz = lm + 1024;                // [256][4]
        #pragma unroll
        for (int mi = 0; mi < 4; ++mi) {
            #pragma unroll
            for (int qq = 0; qq < 4; ++qq) {
                float vb[4]; float m = -3.0e38f;
                #pragma unroll
                for (int nn = 0; nn < 4; ++nn) {
                    const int col = n0 + wc * 64 + nn * 16 + lr;
                    const float vr = bf2f(f2bf(acc[mi][nn][qq] * scale)); // == stored S
                    vb[nn] = (col < N_) ? vr : -3.0e38f;
                    m = fmaxf(m, vb[nn]);
                }
                #pragma unroll
                for (int o = 1; o <= 8; o <<= 1) m = fmaxf(m, __shfl_xor(m, o));
                float z = 0.f;
                #pragma unroll
                for (int nn = 0; nn < 4; ++nn) z += __expf(vb[nn] - m);
                #pragma unroll
                for (int o = 1; o <= 8; o <<= 1) z += __shfl_xor(z, o);
                if (lr == 0) {
                    const int r = wr * 64 + mi * 16 + lh * 4 + qq;
                    lm[r * 4 + wc] = m; lz[r * 4 + wc] = z;
                }
            }
        }
        __syncthreads();
        if (t < 256) {
            const float ma = lm[t * 4 + 0], mb = lm[t * 4 + 1];
            const float mc = lm[t * 4 + 2], md = lm[t * 4 + 3];
            const float M = fmaxf(fmaxf(ma, mb), fmaxf(mc, md));
            const float Z = lz[t * 4 + 0] * __expf(ma - M) + lz[t * 4 + 1] * __expf(mb - M)
                          + lz[t * 4 + 2] * __expf(mc - M) + lz[t * 4 + 3] * __expf(md - M);
            mzp[((long)bz * NP + ty * 256 + t) * 6 + tx] = make_float2(M, Z);
        }
    }
#undef SA_
#undef SB_
}

// -------------------- combine per-block row stats: M_q, 1/Z_q  per (b,row)
__global__ __launch_bounds__(256)
void combine_kernel(const float2* __restrict__ mzp,
                    float* __restrict__ rowM, float* __restrict__ rowZi)
{
    const int i = blockIdx.x * 256 + threadIdx.x;
    if (i >= B_ * NP) return;
    float2 p[6]; float M = -3.0e38f;
    #pragma unroll
    for (int k = 0; k < 6; ++k) { p[k] = mzp[(long)i * 6 + k]; M = fmaxf(M, p[k].x); }
    float Z = 0.f;
    #pragma unroll
    for (int k = 0; k < 6; ++k) Z += p[k].y * __expf(p[k].x - M);
    rowM[i]  = M;
    rowZi[i] = 1.f / Z;
}

// ------- weighted column sums over attn = exp(S - M_q)/Z_q  (softmax fused)
template<int WEIGHTED>
__global__ __launch_bounds__(256)
void colsum_kernel(const __bf16* __restrict__ attn,
                   const float* __restrict__ rowM, const float* __restrict__ rowZi,
                   const float* __restrict__ wv, float* __restrict__ out)
{
    const int t = threadIdx.x;
    if (t >= 192) return;
    const int b  = blockIdx.y;
    const int q0 = blockIdx.x * 16;
    const int q1 = (q0 + 16 < N_) ? q0 + 16 : N_;
    const int k8 = t * 8;
    float s[8] = {};
    const __bf16* base = attn + (long)b * NP * SLD + k8;
    for (int q = q0; q < q1; ++q) {
        bf16x8_t v = *(const bf16x8_t*)(base + (long)q * SLD);
        const float Mq = rowM[b * NP + q];
        float wq = rowZi[b * NP + q];
        if (WEIGHTED) wq *= wv[b * NP + q];
        #pragma unroll
        for (int i = 0; i < 8; ++i) s[i] += wq * __expf(bf2f(v[i]) - Mq);
    }
    #pragma unroll
    for (int i = 0; i < 8; ++i) atomicAdd(out + b * NP + k8 + i, s[i]);
}

// ------------------- pa -> normalize -> curiosity modulation -> fa (output)
__global__ __launch_bounds__(256)
void fa_kernel(const float* __restrict__ pa_raw, const float* __restrict__ curiosity,
               const float* __restrict__ Wc1, const float* __restrict__ bc1,
               const float* __restrict__ Wc2, const float* __restrict__ bc2,
               const float* __restrict__ aw_p,
               float* __restrict__ fa_ws, float* __restrict__ out_fa)
{
    const int b = blockIdx.x, t = threadIdx.x;
    __shared__ float hsh[64];
    __shared__ float red[8];
    __shared__ float cwsh;
    if (t < 64) hsh[t] = fmaxf(0.f, curiosity[b] * Wc1[t] + bc1[t]);
    __syncthreads();
    if (t < 8) {
        float a = bc2[t];
        for (int j = 0; j < 64; ++j) a += hsh[j] * Wc2[j * 8 + t];
        red[t] = 1.f / (1.f + __expf(-a));
    }
    __syncthreads();
    if (t == 0) {
        float cw = 0.f;
        for (int i = 0; i < 8; ++i) cw += red[i];
        cwsh = cw * 0.125f;
    }
    __syncthreads();
    const float aw   = aw_p[0];
    const float modf = 1.f + aw * cwsh;
    const float sig  = 37.f / 6.f;
    const float inv2s2 = 1.f / (2.f * sig * sig);
    float pv[6];
    float s1 = 0.f;
    #pragma unroll
    for (int i = 0; i < 6; ++i) {
        const int k = t + i * 256;
        float p = 0.f;
        if (k < N_) {
            const int y = k / 37, x = k - y * 37;
            const float d2 = (float)((x - 18) * (x - 18) + (y - 18) * (y - 18));
            const float cb = 0.3f * __expf(-d2 * inv2s2);
            p = pa_raw[b * NP + k] * (1.f / 1369.f) + cb;
        }
        pv[i] = p; s1 += p;
    }
    #pragma unroll
    for (int o = 32; o; o >>= 1) s1 += __shfl_xor(s1, o);
    __syncthreads();
    if (!(t & 63)) red[t >> 6] = s1;
    __syncthreads();
    s1 = red[0] + red[1] + red[2] + red[3];
    const float inv1 = 1.f / (s1 + 1e-8f);
    float s2 = 0.f;
    #pragma unroll
    for (int i = 0; i < 6; ++i) {
        const int k = t + i * 256;
        if (k < N_) {
            const float f = fmaxf(pv[i] * inv1 * modf, 1e-8f);
            pv[i] = f; s2 += f;
        }
    }
    #pragma unroll
    for (int o = 32; o; o >>= 1) s2 += __shfl_xor(s2, o);
    if (!(t & 63)) red[4 + (t >> 6)] = s2;
    __syncthreads();
    s2 = red[4] + red[5] + red[6] + red[7];
    const float inv2 = 1.f / (s2 + 1e-8f);
    #pragma unroll
    for (int i = 0; i < 6; ++i) {
        const int k = t + i * 256;
        if (k < N_) {
            const float f = pv[i] * inv2;
            fa_ws[b * NP + k]  = f;
            out_fa[b * N_ + k] = f;
        }
    }
}

// ------------------------------------- weighted[b,d] = sum_k g[b,k]*V[b,k,d]
__global__ __launch_bounds__(256)
void weighted_kernel(const float* __restrict__ g, const __bf16* __restrict__ V,
                     int ldv, float* __restrict__ wout)
{
    const int b  = blockIdx.y;
    const int k0 = blockIdx.x * 86;
    const int k1 = (k0 + 86 < N_) ? k0 + 86 : N_;
    const int d  = threadIdx.x * 4;
    float a0 = 0, a1 = 0, a2 = 0, a3 = 0;
    const __bf16* vb = V + (long)b * NP * ldv + d;
    for (int k = k0; k < k1; ++k) {
        const float gv = g[b * NP + k];
        bf16x4_t vv = *(const bf16x4_t*)(vb + (long)k * ldv);
        a0 += gv * bf2f(vv[0]); a1 += gv * bf2f(vv[1]);
        a2 += gv * bf2f(vv[2]); a3 += gv * bf2f(vv[3]);
    }
    atomicAdd(wout + b * D_ + d + 0, a0);
    atomicAdd(wout + b * D_ + d + 1, a1);
    atomicAdd(wout + b * D_ + d + 2, a2);
    atomicAdd(wout + b * D_ + d + 3, a3);
}

// ---------------- focal stage 1: h[b][j] = relu(weighted@Wp1+bp1), split-K
__global__ __launch_bounds__(256)
void focal1_kernel(const float* __restrict__ weighted, const float* __restrict__ Wp1,
                   const float* __restrict__ bp1, float* __restrict__ h)
{
    const int b = blockIdx.y, jc = blockIdx.x;
    const int t = threadIdx.x;
    const int jl = t >> 2, part = t & 3;
    const int j = jc * 64 + jl;
    const float* wb = weighted + b * 1024 + part * 256;
    const float* wp = Wp1 + (long)(part * 256) * 512 + j;
    float a = 0.f;
    #pragma unroll 8
    for (int d = 0; d < 256; ++d) a += wb[d] * wp[(long)d * 512];
    a += __shfl_xor(a, 1);
    a += __shfl_xor(a, 2);
    if (part == 0) h[b * 512 + j] = fmaxf(a + bp1[j], 0.f);
}

// ---------------- focal stage 2: out = h@Wp2 + bp2 (coalesced Wp2 rows)
__global__ __launch_bounds__(128)
void focal2_kernel(const float* __restrict__ h, const float* __restrict__ Wp2,
                   const float* __restrict__ bp2, float* __restrict__ out)
{
    const int b = blockIdx.x, o = threadIdx.x;
    __shared__ float hs[512];
    for (int i = o; i < 512; i += 128) hs[i] = h[b * 512 + i];
    __syncthreads();
    float a = bp2[o];
    #pragma unroll 8
    for (int j = 0; j < 512; ++j) a += hs[j] * Wp2[j * 128 + o];
    out[b * 128 + o] = a;
}

// ---------------------------------------------------------------- launcher
extern "C" void kernel_launch(void* const* d_in, const int* in_sizes, int n_in,
                              void* d_out, int out_size, void* d_ws, size_t ws_size,
                              hipStream_t stream)
{
    const float* patch     = (const float*)d_in[0];
    const float* curiosity = (const float*)d_in[1];
    const float* Wq  = (const float*)d_in[2];
    const float* bq  = (const float*)d_in[3];
    const float* Wk  = (const float*)d_in[4];
    const float* bk  = (const float*)d_in[5];
    const float* Wv  = (const float*)d_in[6];
    const float* bv  = (const float*)d_in[7];
    const float* Wc1 = (const float*)d_in[8];
    const float* bc1 = (const float*)d_in[9];
    const float* Wc2 = (const float*)d_in[10];
    const float* bc2 = (const float*)d_in[11];
    const float* Wp1 = (const float*)d_in[12];
    const float* bp1 = (const float*)d_in[13];
    const float* Wp2 = (const float*)d_in[14];
    const float* bp2 = (const float*)d_in[15];
    const float* aw  = (const float*)d_in[16];
    float* out = (float*)d_out;

    char* ws = (char*)d_ws;
    size_t off = 0;
    auto alloc = [&](size_t bytes) -> char* {
        char* p = ws + off;
        off += (bytes + 255) & ~(size_t)255;
        return p;
    };
    // region 0: {pos, X, WT} -- later aliased by S (all fully rewritten each call)
    float*  pos  = (float*) alloc((size_t)N_ * D_ * 4);
    __bf16* X    = (__bf16*)alloc((size_t)B_ * NP * D_ * 2);
    __bf16* WT   = (__bf16*)alloc((size_t)3 * D_ * D_ * 2);
    const size_t S_BYTES = (size_t)B_ * NP * SLD * 2;
    if (off < S_BYTES) off = S_BYTES;
    __bf16* S    = (__bf16*)ws;                                         // alias region 0
    __bf16* QKV  = (__bf16*)alloc((size_t)B_ * NP * QLD * 2);
    float*  pa   = (float*) alloc((size_t)B_ * NP * 4);
    float*  faw  = (float*) alloc((size_t)B_ * NP * 4);
    float*  gbuf = (float*) alloc((size_t)B_ * NP * 4);
    float*  wsum = (float*) alloc((size_t)B_ * D_ * 4);
    float*  bcat = (float*) alloc((size_t)NQKV * 4);
    float*  hbuf = (float*) alloc((size_t)B_ * 512 * 4);
    float2* mzp  = (float2*)alloc((size_t)B_ * NP * 6 * 8);
    float*  rowM = (float*) alloc((size_t)B_ * NP * 4);
    float*  rowZi= (float*) alloc((size_t)B_ * NP * 4);

    (void)hipMemsetAsync(pa,   0, (size_t)B_ * NP * 4, stream);
    (void)hipMemsetAsync(gbuf, 0, (size_t)B_ * NP * 4, stream);
    (void)hipMemsetAsync(wsum, 0, (size_t)B_ * D_ * 4, stream);

    pos_kernel<<<(N_ * D_ + 255) / 256, 256, 0, stream>>>(pos);
    addpos_kernel<<<(int)((size_t)B_ * NP * D_ / 4 / 256), 256, 0, stream>>>(patch, pos, X);
    {
        dim3 g(16, 16, 3);
        wcast_kernel<<<g, 256, 0, stream>>>(Wq, Wk, Wv,
                                            WT, WT + D_ * D_, WT + 2 * D_ * D_);
    }
    bcat_kernel<<<(NQKV + 255) / 256, 256, 0, stream>>>(bq, bk, bv, bcat);
    {
        // QKV projection: M=24576(96), N=3072(12), K=1024 -> 1152 blocks
        const int nwg = 96 * 12;
        gemm256<1, 0><<<nwg, 1024, 0, stream>>>(X, WT, QKV, bcat, nullptr,
                                                D_, D_, QLD, D_, 1.0f,
                                                0, 0, 0, 12, nwg, nwg / 8);
    }
    {
        // scores: per batch M=N=1536(6x6), K=1024; 16 batches -> 576 blocks
        const int nwg = 36 * B_;
        gemm256<0, 1><<<nwg, 1024, 0, stream>>>(QKV, QKV + D_, S, nullptr, mzp,
                                                QLD, QLD, SLD, D_,
                                                0.08838834764831845f,
                                                (long)NP * QLD, (long)NP * QLD,
                                                (long)NP * SLD, 6, 36, nwg / 8);
    }
    combine_kernel<<<(B_ * NP + 255) / 256, 256, 0, stream>>>(mzp, rowM, rowZi);
    {
        dim3 g(86, B_);
        colsum_kernel<0><<<g, 256, 0, stream>>>(S, rowM, rowZi, nullptr, pa);
    }
    fa_kernel<<<B_, 256, 0, stream>>>(pa, curiosity, Wc1, bc1, Wc2, bc2, aw,
                                      faw, out + B_ * 128);
    {
        dim3 g(86, B_);
        colsum_kernel<1><<<g, 256, 0, stream>>>(S, rowM, rowZi, faw, gbuf);
    }
    {
        dim3 g(16, B_);
        weighted_kernel<<<g, 256, 0, stream>>>(gbuf, QKV + 2 * D_, QLD, wsum);
    }
    {
        dim3 g(8, B_);
        focal1_kernel<<<g, 256, 0, stream>>>(wsum, Wp1, bp1, hbuf);
    }
    focal2_kernel<<<B_, 128, 0, stream>>>(hbuf, Wp2, bp2, out);
}

// Round 9
// 551.272 us; speedup vs baseline: 1.1209x; 1.0026x over previous
//
#include <hip/hip_runtime.h>
#include <hip/hip_bf16.h>
#include <cstdint>

#define B_   16
#define N_   1369
#define NP   1536
#define D_   1024
#define NQK  2048
#define SLD  1568   // S leading dim (3136B rows: odd multiple of 64B)
#define QLD  2080   // QK leading dim (4160B rows: odd multiple of 64B)

typedef __bf16 bf16x8_t __attribute__((ext_vector_type(8)));
typedef __bf16 bf16x4_t __attribute__((ext_vector_type(4)));
typedef float  f32x4_t  __attribute__((ext_vector_type(4)));

__device__ __forceinline__ float  bf2f(__bf16 x) { return (float)x; }
__device__ __forceinline__ __bf16 f2bf(float x)  { return (__bf16)x; }

#define GLOAD_LDS16(g, l) __builtin_amdgcn_global_load_lds( \
    (const __attribute__((address_space(1))) void*)(g),     \
    (__attribute__((address_space(3))) void*)(l), 16, 0, 0)

// ---------------------------------------------------------------- pos table
__global__ __launch_bounds__(256)
void pos_kernel(float* __restrict__ pos)
{
    const int idx = blockIdx.x * 256 + threadIdx.x;
    if (idx >= N_ * D_) return;
    const int n = idx >> 10, f = idx & 1023;
    const int row = n / 37, col = n - row * 37;
    const float base = (f < 512) ? (float)row : (float)col;
    const int  t2   = (f & 511) >> 1;
    const float dv  = __expf(-0.03597789207803197f * (float)t2);
    const float ang = base * dv;
    pos[idx] = (f & 1) ? cosf(ang) : sinf(ang);
}

// ----------------------------------------------- x = patch + pos, cast bf16
__global__ __launch_bounds__(256)
void addpos_kernel(const float* __restrict__ patch, const float* __restrict__ pos,
                   __bf16* __restrict__ X)
{
    const long tid = (long)blockIdx.x * 256 + threadIdx.x;
    const long e   = tid * 4;
    const int  f   = (int)(e & 1023);
    const long nb  = e >> 10;
    const int  n   = (int)(nb % NP);
    const long b   = nb / NP;
    bf16x4_t o;
    if (n < N_) {
        const float4 p = *(const float4*)(patch + ((b * N_ + n) << 10) + f);
        const float4 q = *(const float4*)(pos + ((long)n << 10) + f);
        o[0] = f2bf(p.x + q.x); o[1] = f2bf(p.y + q.y);
        o[2] = f2bf(p.z + q.z); o[3] = f2bf(p.w + q.w);
    } else {
        o[0] = o[1] = o[2] = o[3] = f2bf(0.f);
    }
    *(bf16x4_t*)(X + e) = o;
}

// ---------------------------------- W[i][o] -> WT[o][i] bf16 (Wq, Wk only)
__global__ __launch_bounds__(256)
void wcast_kernel(const float* __restrict__ W0, const float* __restrict__ W1,
                  __bf16* __restrict__ T0, __bf16* __restrict__ T1)
{
    const float* W = blockIdx.z == 0 ? W0 : W1;
    __bf16*      T = blockIdx.z == 0 ? T0 : T1;
    __shared__ float tile[64][65];
    const int o0 = blockIdx.x * 64, i0 = blockIdx.y * 64;
    const int t = threadIdx.x;
    const int tr = t >> 4, tc = (t & 15) * 4;
    #pragma unroll
    for (int rr = 0; rr < 64; rr += 16) {
        float4 v = *(const float4*)(W + (long)(i0 + rr + tr) * 1024 + o0 + tc);
        tile[rr + tr][tc + 0] = v.x; tile[rr + tr][tc + 1] = v.y;
        tile[rr + tr][tc + 2] = v.z; tile[rr + tr][tc + 3] = v.w;
    }
    __syncthreads();
    #pragma unroll
    for (int rr = 0; rr < 64; rr += 16) {
        bf16x4_t o;
        o[0] = f2bf(tile[tc + 0][rr + tr]); o[1] = f2bf(tile[tc + 1][rr + tr]);
        o[2] = f2bf(tile[tc + 2][rr + tr]); o[3] = f2bf(tile[tc + 3][rr + tr]);
        *(bf16x4_t*)(T + (long)(o0 + rr + tr) * 1024 + i0 + tc) = o;
    }
}

// ------------------------------------------------- bias concat [bq|bk] 2048
__global__ __launch_bounds__(256)
void bcat_kernel(const float* __restrict__ bq, const float* __restrict__ bk,
                 float* __restrict__ bcat)
{
    const int i = blockIdx.x * 256 + threadIdx.x;
    if (i >= NQK) return;
    bcat[i] = (i < 1024) ? bq[i] : bk[i - 1024];
}

// --------------------------- 256^2 GEMM body, 16 waves (4x4), double-buffer
// (r8-proven, 41.8% MfmaUtil, 0 bank conflicts.) STATS=1: scores variant --
// masked per-row {max, sum-exp} partials to mzp + guarded C stores
// (row<N_ && col<N_; unwritten S pad cells keep 0xAA poison = -2.4e-13,
// finite, only ever read into unread pa[k>=N_] slots).
template<int HAS_BIAS, int STATS>
__device__ __forceinline__
void gemm_body(const __bf16* __restrict__ A, const __bf16* __restrict__ Bt,
               __bf16* __restrict__ C, const float* __restrict__ bias,
               float2* __restrict__ mzp,
               int lda, int ldb, int ldc, int Kd, float scale,
               long sA, long sB, long sC, int tilesN, int tilesPerBatch, int cpx)
{
    __shared__ __bf16 lds[65536];   // 128 KiB: buf c at c*32768 (A +0, B +16384)
    const int bid = blockIdx.x;
    const int vt  = (bid & 7) * cpx + (bid >> 3);      // XCD-bijective (nwg%8==0)
    const int bz  = vt / tilesPerBatch;
    const int rem = vt - bz * tilesPerBatch;
    const int ty  = rem / tilesN;
    const int tx  = rem - ty * tilesN;
    A  += (long)bz * sA;  Bt += (long)bz * sB;  C += (long)bz * sC;
    const int m0 = ty * 256, n0 = tx * 256;

    const int t  = threadIdx.x;
    const int w  = t >> 6, l = t & 63;
    const int wr = w >> 2, wc = w & 3;         // 4 x 4 wave grid
    const int lr = l & 15, lh = l >> 4;

    const int laneF  = (lr * 64 + ((lh * 16) ^ (((lr >> 3) & 1) << 5))) >> 1;
    // staging (16 waves, 1 gload/half): wave w -> rowgroup w>>1, khalf w&1;
    // lane l -> row_local l>>2, k_local (l&3)*8, swizzle XOR when l>=32.
    const int rstage = (w >> 1) * 16 + (l >> 2);
    const int kstage = (w & 1) * 32 + (((l & 3) * 8) ^ (((l >> 5) & 1) << 4));

    const __bf16* Ag = A  + (long)(m0 + rstage) * lda + kstage;
    const __bf16* Bg = Bt + (long)(n0 + rstage) * ldb + kstage;
    __bf16* dA = lds + w * 512;
    __bf16* dB = lds + 16384 + w * 512;

#define SA_(buf, half, kt) GLOAD_LDS16(Ag + (long)(half) * 128 * lda + (kt) * 64, \
                                       dA + (buf) * 32768 + (half) * 8192)
#define SB_(buf, half, kt) GLOAD_LDS16(Bg + (long)(half) * 128 * ldb + (kt) * 64, \
                                       dB + (buf) * 32768 + (half) * 8192)

    f32x4_t acc[4][4] = {};

    const int NT = Kd >> 6;
    SA_(0, 0, 0); SA_(0, 1, 0); SB_(0, 0, 0); SB_(0, 1, 0);
    asm volatile("s_waitcnt vmcnt(0)" ::: "memory");
    __builtin_amdgcn_s_barrier();

    for (int tk = 0; tk < NT; ++tk) {
        const int c = tk & 1, o = c ^ 1;
        if (tk + 1 < NT) {
            SA_(o, 0, tk + 1); SA_(o, 1, tk + 1);
            SB_(o, 0, tk + 1); SB_(o, 1, tk + 1);
        }
        const int cb = c * 32768;
        const __bf16* ap = lds + cb + (wr >> 1) * 8192 + (wr & 1) * 4096 + laneF;
        const __bf16* bp = lds + cb + 16384 + (wc >> 1) * 8192 + (wc & 1) * 4096 + laneF;
        bf16x8_t af[4], bfm[4];
        #pragma unroll
        for (int nn = 0; nn < 4; ++nn) bfm[nn] = *(const bf16x8_t*)(bp + nn * 1024);
        #pragma unroll
        for (int mi = 0; mi < 4; ++mi) af[mi]  = *(const bf16x8_t*)(ap + mi * 1024);
        __builtin_amdgcn_s_setprio(1);
        #pragma unroll
        for (int mi = 0; mi < 4; ++mi)
            #pragma unroll
            for (int nn = 0; nn < 4; ++nn)
                acc[mi][nn] = __builtin_amdgcn_mfma_f32_16x16x32_bf16(af[mi], bfm[nn], acc[mi][nn], 0, 0, 0);
        __builtin_amdgcn_s_setprio(0);
        #pragma unroll
        for (int nn = 0; nn < 4; ++nn) bfm[nn] = *(const bf16x8_t*)(bp + nn * 1024 + 512);
        #pragma unroll
        for (int mi = 0; mi < 4; ++mi) af[mi]  = *(const bf16x8_t*)(ap + mi * 1024 + 512);
        __builtin_amdgcn_s_setprio(1);
        #pragma unroll
        for (int mi = 0; mi < 4; ++mi)
            #pragma unroll
            for (int nn = 0; nn < 4; ++nn)
                acc[mi][nn] = __builtin_amdgcn_mfma_f32_16x16x32_bf16(af[mi], bfm[nn], acc[mi][nn], 0, 0, 0);
        __builtin_amdgcn_s_setprio(0);
        asm volatile("s_waitcnt vmcnt(0)" ::: "memory");
        __builtin_amdgcn_s_barrier();
    }

    // epilogue: C/D layout col=lane&15, row=(lane>>4)*4+reg
    #pragma unroll
    for (int mi = 0; mi < 4; ++mi) {
        const int row = m0 + wr * 64 + mi * 16 + lh * 4;
        #pragma unroll
        for (int nn = 0; nn < 4; ++nn) {
            const int col = n0 + wc * 64 + nn * 16 + lr;
            const float bb = HAS_BIAS ? bias[col] : 0.0f;
            #pragma unroll
            for (int q = 0; q < 4; ++q) {
                if (!STATS || ((row + q) < N_ && col < N_))
                    C[(long)(row + q) * ldc + col] = f2bf(acc[mi][nn][q] * scale + bb);
            }
        }
    }

    if (STATS) {
        __syncthreads();                      // safe to reuse lds
        float* lm = (float*)lds;              // [256][4]
        float* lz = lm + 1024;                // [256][4]
        #pragma unroll
        for (int mi = 0; mi < 4; ++mi) {
            #pragma unroll
            for (int qq = 0; qq < 4; ++qq) {
                float vb[4]; float m = -3.0e38f;
                #pragma unroll
                for (int nn = 0; nn < 4; ++nn) {
                    const int col = n0 + wc * 64 + nn * 16 + lr;
                    const float vr = bf2f(f2bf(acc[mi][nn][qq] * scale)); // == stored S
                    vb[nn] = (col < N_) ? vr : -3.0e38f;
                    m = fmaxf(m, vb[nn]);
                }
                #pragma unroll
                for (int o = 1; o <= 8; o <<= 1) m = fmaxf(m, __shfl_xor(m, o));
                float z = 0.f;
                #pragma unroll
                for (int nn = 0; nn < 4; ++nn) z += __expf(vb[nn] - m);
                #pragma unroll
                for (int o = 1; o <= 8; o <<= 1) z += __shfl_xor(z, o);
                if (lr == 0) {
                    const int r = wr * 64 + mi * 16 + lh * 4 + qq;
                    lm[r * 4 + wc] = m; lz[r * 4 + wc] = z;
                }
            }
        }
        __syncthreads();
        if (t < 256) {
            const float ma = lm[t * 4 + 0], mb = lm[t * 4 + 1];
            const float mc = lm[t * 4 + 2], md = lm[t * 4 + 3];
            const float M = fmaxf(fmaxf(ma, mb), fmaxf(mc, md));
            const float Z = lz[t * 4 + 0] * __expf(ma - M) + lz[t * 4 + 1] * __expf(mb - M)
                          + lz[t * 4 + 2] * __expf(mc - M) + lz[t * 4 + 3] * __expf(md - M);
            mzp[((long)bz * NP + ty * 256 + t) * 6 + tx] = make_float2(M, Z);
        }
    }
#undef SA_
#undef SB_
}

// named instantiations so rocprof disambiguates the two GEMMs
__global__ __launch_bounds__(1024, 4)
void gemm_qk(const __bf16* A, const __bf16* Bt, __bf16* C, const float* bias,
             int lda, int ldb, int ldc, int Kd,
             int tilesN, int tilesPerBatch, int cpx)
{
    gemm_body<1, 0>(A, Bt, C, bias, nullptr, lda, ldb, ldc, Kd, 1.0f,
                    0, 0, 0, tilesN, tilesPerBatch, cpx);
}

__global__ __launch_bounds__(1024, 4)
void gemm_sc(const __bf16* A, const __bf16* Bt, __bf16* C, float2* mzp,
             int lda, int ldb, int ldc, int Kd, float scale,
             long sA, long sB, long sC, int tilesN, int tilesPerBatch, int cpx)
{
    gemm_body<0, 1>(A, Bt, C, nullptr, mzp, lda, ldb, ldc, Kd, scale,
                    sA, sB, sC, tilesN, tilesPerBatch, cpx);
}

// ---- weighted column sums over attn = exp(S - M_q)/Z_q (softmax + combine
// fused; per-block 16-row stats derived inline from mzp).
template<int WEIGHTED>
__global__ __launch_bounds__(256)
void colsum_kernel(const __bf16* __restrict__ attn, const float2* __restrict__ mzp,
                   const float* __restrict__ wv, float* __restrict__ out)
{
    const int t  = threadIdx.x;
    const int b  = blockIdx.y;
    const int q0 = blockIdx.x * 16;
    __shared__ float sM[16], sZi[16];
    if (t < 16) {
        const int q = q0 + t;
        float M = -3.0e38f, Zi = 1.f;
        if (q < N_) {
            float2 p[6];
            #pragma unroll
            for (int k = 0; k < 6; ++k) { p[k] = mzp[((long)b * NP + q) * 6 + k]; M = fmaxf(M, p[k].x); }
            float Z = 0.f;
            #pragma unroll
            for (int k = 0; k < 6; ++k) Z += p[k].y * __expf(p[k].x - M);
            Zi = 1.f / Z;
        }
        sM[t] = M; sZi[t] = Zi;
    }
    __syncthreads();
    const int k8 = t * 8;
    if (k8 < N_) {
        const int q1 = (q0 + 16 < N_) ? q0 + 16 : N_;
        float s[8] = {};
        const __bf16* base = attn + (long)b * NP * SLD + k8;
        for (int q = q0; q < q1; ++q) {
            bf16x8_t v = *(const bf16x8_t*)(base + (long)q * SLD);
            const float Mq = sM[q - q0];
            float wq = sZi[q - q0];
            if (WEIGHTED) wq *= wv[b * NP + q];
            #pragma unroll
            for (int i = 0; i < 8; ++i) s[i] += wq * __expf(bf2f(v[i]) - Mq);
        }
        #pragma unroll
        for (int i = 0; i < 8; ++i) atomicAdd(out + b * NP + k8 + i, s[i]);
    }
}

// ------------------- pa -> normalize -> curiosity modulation -> fa (output)
__global__ __launch_bounds__(256)
void fa_kernel(const float* __restrict__ pa_raw, const float* __restrict__ curiosity,
               const float* __restrict__ Wc1, const float* __restrict__ bc1,
               const float* __restrict__ Wc2, const float* __restrict__ bc2,
               const float* __restrict__ aw_p,
               float* __restrict__ fa_ws, float* __restrict__ out_fa)
{
    const int b = blockIdx.x, t = threadIdx.x;
    __shared__ float hsh[64];
    __shared__ float red[8];
    __shared__ float cwsh;
    if (t < 64) hsh[t] = fmaxf(0.f, curiosity[b] * Wc1[t] + bc1[t]);
    __syncthreads();
    if (t < 8) {
        float a = bc2[t];
        for (int j = 0; j < 64; ++j) a += hsh[j] * Wc2[j * 8 + t];
        red[t] = 1.f / (1.f + __expf(-a));
    }
    __syncthreads();
    if (t == 0) {
        float cw = 0.f;
        for (int i = 0; i < 8; ++i) cw += red[i];
        cwsh = cw * 0.125f;
    }
    __syncthreads();
    const float aw   = aw_p[0];
    const float modf = 1.f + aw * cwsh;
    const float sig  = 37.f / 6.f;
    const float inv2s2 = 1.f / (2.f * sig * sig);
    float pv[6];
    float s1 = 0.f;
    #pragma unroll
    for (int i = 0; i < 6; ++i) {
        const int k = t + i * 256;
        float p = 0.f;
        if (k < N_) {
            const int y = k / 37, x = k - y * 37;
            const float d2 = (float)((x - 18) * (x - 18) + (y - 18) * (y - 18));
            const float cb = 0.3f * __expf(-d2 * inv2s2);
            p = pa_raw[b * NP + k] * (1.f / 1369.f) + cb;
        }
        pv[i] = p; s1 += p;
    }
    #pragma unroll
    for (int o = 32; o; o >>= 1) s1 += __shfl_xor(s1, o);
    __syncthreads();
    if (!(t & 63)) red[t >> 6] = s1;
    __syncthreads();
    s1 = red[0] + red[1] + red[2] + red[3];
    const float inv1 = 1.f / (s1 + 1e-8f);
    float s2 = 0.f;
    #pragma unroll
    for (int i = 0; i < 6; ++i) {
        const int k = t + i * 256;
        if (k < N_) {
            const float f = fmaxf(pv[i] * inv1 * modf, 1e-8f);
            pv[i] = f; s2 += f;
        }
    }
    #pragma unroll
    for (int o = 32; o; o >>= 1) s2 += __shfl_xor(s2, o);
    if (!(t & 63)) red[4 + (t >> 6)] = s2;
    __syncthreads();
    s2 = red[4] + red[5] + red[6] + red[7];
    const float inv2 = 1.f / (s2 + 1e-8f);
    #pragma unroll
    for (int i = 0; i < 6; ++i) {
        const int k = t + i * 256;
        if (k < N_) {
            const float f = pv[i] * inv2;
            fa_ws[b * NP + k]  = f;
            out_fa[b * N_ + k] = f;
        }
    }
}

// ---------------- u[b][d] = sum_k g[b,k]*X[b,k,d]  (+ gsum[b] = sum_k g)
// V-projection eliminated: weighted = u@Wv + gsum*bv (GEMV below).
__global__ __launch_bounds__(256)
void u_kernel(const float* __restrict__ g, const __bf16* __restrict__ X,
              float* __restrict__ u, float* __restrict__ gsum)
{
    const int b  = blockIdx.y;
    const int k0 = blockIdx.x * 86;
    const int k1 = (k0 + 86 < N_) ? k0 + 86 : N_;
    const int d  = threadIdx.x * 4;
    float a0 = 0, a1 = 0, a2 = 0, a3 = 0, gs = 0;
    const __bf16* xb = X + (long)b * NP * D_ + d;
    for (int k = k0; k < k1; ++k) {
        const float gv = g[b * NP + k];
        bf16x4_t xv = *(const bf16x4_t*)(xb + (long)k * D_);
        a0 += gv * bf2f(xv[0]); a1 += gv * bf2f(xv[1]);
        a2 += gv * bf2f(xv[2]); a3 += gv * bf2f(xv[3]);
        gs += gv;
    }
    atomicAdd(u + b * D_ + d + 0, a0);
    atomicAdd(u + b * D_ + d + 1, a1);
    atomicAdd(u + b * D_ + d + 2, a2);
    atomicAdd(u + b * D_ + d + 3, a3);
    if (threadIdx.x == 0) atomicAdd(gsum + b, gs);
}

// ---------------- weighted[b][d] = u[b]@Wv[:,d] + gsum[b]*bv[d]  (fp32 GEMV)
__global__ __launch_bounds__(256)
void wv_gemv_kernel(const float* __restrict__ u, const float* __restrict__ gsum,
                    const float* __restrict__ Wv, const float* __restrict__ bv,
                    float* __restrict__ wout)
{
    const int dcx = blockIdx.x, b = blockIdx.y;
    const int t = threadIdx.x;
    __shared__ float us[1024];
    #pragma unroll
    for (int i = 0; i < 4; ++i) us[t + i * 256] = u[b * D_ + t + i * 256];
    __syncthreads();
    const int d = dcx * 256 + t;
    float a = gsum[b] * bv[d];
    #pragma unroll 8
    for (int i = 0; i < 1024; ++i) a += us[i] * Wv[(long)i * 1024 + d];
    wout[b * D_ + d] = a;
}

// ---------------- focal stage 1: h[b][j] = relu(weighted@Wp1+bp1), split-K
__global__ __launch_bounds__(256)
void focal1_kernel(const float* __restrict__ weighted, const float* __restrict__ Wp1,
                   const float* __restrict__ bp1, float* __restrict__ h)
{
    const int b = blockIdx.y, jc = blockIdx.x;
    const int t = threadIdx.x;
    const int jl = t >> 2, part = t & 3;
    const int j = jc * 64 + jl;
    const float* wb = weighted + b * 1024 + part * 256;
    const float* wp = Wp1 + (long)(part * 256) * 512 + j;
    float a = 0.f;
    #pragma unroll 8
    for (int d = 0; d < 256; ++d) a += wb[d] * wp[(long)d * 512];
    a += __shfl_xor(a, 1);
    a += __shfl_xor(a, 2);
    if (part == 0) h[b * 512 + j] = fmaxf(a + bp1[j], 0.f);
}

// ---------------- focal stage 2: out = h@Wp2 + bp2 (coalesced Wp2 rows)
__global__ __launch_bounds__(128)
void focal2_kernel(const float* __restrict__ h, const float* __restrict__ Wp2,
                   const float* __restrict__ bp2, float* __restrict__ out)
{
    const int b = blockIdx.x, o = threadIdx.x;
    __shared__ float hs[512];
    for (int i = o; i < 512; i += 128) hs[i] = h[b * 512 + i];
    __syncthreads();
    float a = bp2[o];
    #pragma unroll 8
    for (int j = 0; j < 512; ++j) a += hs[j] * Wp2[j * 128 + o];
    out[b * 128 + o] = a;
}

// ---------------------------------------------------------------- launcher
extern "C" void kernel_launch(void* const* d_in, const int* in_sizes, int n_in,
                              void* d_out, int out_size, void* d_ws, size_t ws_size,
                              hipStream_t stream)
{
    const float* patch     = (const float*)d_in[0];
    const float* curiosity = (const float*)d_in[1];
    const float* Wq  = (const float*)d_in[2];
    const float* bq  = (const float*)d_in[3];
    const float* Wk  = (const float*)d_in[4];
    const float* bk  = (const float*)d_in[5];
    const float* Wv  = (const float*)d_in[6];
    const float* bv  = (const float*)d_in[7];
    const float* Wc1 = (const float*)d_in[8];
    const float* bc1 = (const float*)d_in[9];
    const float* Wc2 = (const float*)d_in[10];
    const float* bc2 = (const float*)d_in[11];
    const float* Wp1 = (const float*)d_in[12];
    const float* bp1 = (const float*)d_in[13];
    const float* Wp2 = (const float*)d_in[14];
    const float* bp2 = (const float*)d_in[15];
    const float* aw  = (const float*)d_in[16];
    float* out = (float*)d_out;

    char* ws = (char*)d_ws;
    size_t off = 0;
    auto alloc = [&](size_t bytes) -> char* {
        char* p = ws + off;
        off += (bytes + 255) & ~(size_t)255;
        return p;
    };
    float*  pos  = (float*) alloc((size_t)N_ * D_ * 4);                 // 5.6 MB
    __bf16* X    = (__bf16*)alloc((size_t)B_ * NP * D_ * 2);            // 50.3 MB (alive to end)
    __bf16* WT   = (__bf16*)alloc((size_t)2 * D_ * D_ * 2);             // 4.2 MB
    __bf16* S    = (__bf16*)alloc((size_t)B_ * NP * SLD * 2);           // 77.1 MB
    __bf16* QK   = (__bf16*)alloc((size_t)B_ * NP * QLD * 2);           // 102.2 MB
    // zero-init region (single memset): pa | gbuf | ubuf | gsum
    float*  pa   = (float*) alloc((size_t)B_ * NP * 4);
    float*  gbuf = (float*) alloc((size_t)B_ * NP * 4);
    float*  ubuf = (float*) alloc((size_t)B_ * D_ * 4);
    float*  gsum = (float*) alloc((size_t)B_ * 4);
    const size_t zbytes = (size_t)((char*)(gsum + B_) - (char*)pa);
    float*  faw  = (float*) alloc((size_t)B_ * NP * 4);
    float*  bcat = (float*) alloc((size_t)NQK * 4);
    float*  hbuf = (float*) alloc((size_t)B_ * 512 * 4);
    float2* mzp  = (float2*)alloc((size_t)B_ * NP * 6 * 8);
    float*  wsum = (float*) alloc((size_t)B_ * D_ * 4);

    (void)hipMemsetAsync(pa, 0, zbytes, stream);

    pos_kernel<<<(N_ * D_ + 255) / 256, 256, 0, stream>>>(pos);
    addpos_kernel<<<(int)((size_t)B_ * NP * D_ / 4 / 256), 256, 0, stream>>>(patch, pos, X);
    {
        dim3 g(16, 16, 2);
        wcast_kernel<<<g, 256, 0, stream>>>(Wq, Wk, WT, WT + D_ * D_);
    }
    bcat_kernel<<<(NQK + 255) / 256, 256, 0, stream>>>(bq, bk, bcat);
    {
        // QK projection: M=B*NP=24576(96), N=2048(8), K=1024 -> 768 blocks
        const int nwg = 96 * 8;
        gemm_qk<<<nwg, 1024, 0, stream>>>(X, WT, QK, bcat,
                                          D_, D_, QLD, D_, 8, nwg, nwg / 8);
    }
    {
        // scores: per batch M=N=1536(6x6), K=1024; 16 batches -> 576 blocks
        const int nwg = 36 * B_;
        gemm_sc<<<nwg, 1024, 0, stream>>>(QK, QK + 1024, S, mzp,
                                          QLD, QLD, SLD, D_,
                                          0.08838834764831845f,
                                          (long)NP * QLD, (long)NP * QLD,
                                          (long)NP * SLD, 6, 36, nwg / 8);
    }
    {
        dim3 g(86, B_);
        colsum_kernel<0><<<g, 256, 0, stream>>>(S, mzp, nullptr, pa);
    }
    fa_kernel<<<B_, 256, 0, stream>>>(pa, curiosity, Wc1, bc1, Wc2, bc2, aw,
                                      faw, out + B_ * 128);
    {
        dim3 g(86, B_);
        colsum_kernel<1><<<g, 256, 0, stream>>>(S, mzp, faw, gbuf);
    }
    {
        dim3 g(16, B_);
        u_kernel<<<g, 256, 0, stream>>>(gbuf, X, ubuf, gsum);
    }
    {
        dim3 g(4, B_);
        wv_gemv_kernel<<<g, 256, 0, stream>>>(ubuf, gsum, Wv, bv, wsum);
    }
    {
        dim3 g(8, B_);
        focal1_kernel<<<g, 256, 0, stream>>>(wsum, Wp1, bp1, hbuf);
    }
    focal2_kernel<<<B_, 128, 0, stream>>>(hbuf, Wp2, bp2, out);
}